// Round 9
// baseline (348.295 us; speedup 1.0000x reference)
//
#include <hip/hip_runtime.h>
#include <math.h>

typedef short v8s __attribute__((ext_vector_type(8)));
typedef float v4f __attribute__((ext_vector_type(4)));

#define NVOX 64000      // 40^3
#define NPAD 74088      // 42^3
#define P2   1764       // 42^2
#define GSTR 592704     // NPAD*8
#define NCPY 32         // banked global-accumulator copies
#define ITST (NCPY*260) // stride per kmeans iteration (8320 floats)

__device__ __forceinline__ unsigned short bf16rne(float f){
  unsigned int u = __float_as_uint(f);
  u += 0x7FFFu + ((u >> 16) & 1u);
  return (unsigned short)(u >> 16);
}

// ---------------- merged prep: projection (blocks 0..999, 4-way channel split)
// + base_w bf16 repack (blocks 1000..1431) + xpt halo zeroing (blocks 1432..1471).
__global__ __launch_bounds__(256) void prep_k(const float* __restrict__ x,
                                              const float* __restrict__ pw,
                                              float* __restrict__ xp,
                                              short* __restrict__ xpt,
                                              const float* __restrict__ bw,
                                              short* __restrict__ bwb){
  int tid = threadIdx.x;
  int bid = blockIdx.x;
  if (bid < 1000){
    int m = (bid >> 2) * 256 + tid;
    int quarter = bid & 3;
    float xv[64];
#pragma unroll
    for (int i = 0; i < 64; i++) xv[i] = x[(size_t)i * NVOX + m];
    int d = m / 1600; int r = m - d * 1600; int h = r / 40; int w = r - h * 40;
    int p = ((d + 1) * 42 + (h + 1)) * 42 + (w + 1);
    const float4* pw4 = (const float4*)pw;
    for (int g8 = quarter * 2; g8 < quarter * 2 + 2; g8++){
      v8s pk;
#pragma unroll
      for (int j = 0; j < 8; j++){
        int co = g8 * 8 + j;
        float acc = 0.f;
#pragma unroll
        for (int q = 0; q < 16; q++){
          float4 pv = pw4[co * 16 + q];   // wave-uniform -> scalar K$ loads
          acc = fmaf(pv.x, xv[4*q+0], acc);
          acc = fmaf(pv.y, xv[4*q+1], acc);
          acc = fmaf(pv.z, xv[4*q+2], acc);
          acc = fmaf(pv.w, xv[4*q+3], acc);
        }
        xp[(size_t)co * NVOX + m] = acc;
        pk[j] = (short)bf16rne(acc);
      }
      *(v8s*)(xpt + (size_t)g8 * GSTR + (size_t)p * 8) = pk;
    }
  } else if (bid < 1432){
    int e = (bid - 1000) * 256 + tid;               // 0 .. 110591
    int t5 = e >> 12; int rem = e & 4095;
    int o = rem >> 6; int c = rem & 63;
    bwb[e] = (short)bf16rne(bw[(o * 64 + c) * 27 + t5]);
  } else {
    v8s z = (v8s){0,0,0,0,0,0,0,0};
    for (int p = (bid - 1432) * 256 + tid; p < NPAD; p += 40 * 256){
      int d = p / P2; int rem = p - d * P2; int h = rem / 42; int w = rem - h * 42;
      if (d == 0 || d == 41 || h == 0 || h == 41 || w == 0 || w == 41){
#pragma unroll
        for (int g = 0; g < 8; g++)
          *(v8s*)(xpt + (size_t)g * GSTR + (size_t)p * 8) = z;
      }
    }
  }
}

// ---------------- fused w+h box passes per (c,d) slice (zero pad) — R6-proven
__global__ __launch_bounds__(256) void boxwh_k(const float* __restrict__ in,
                                               float* __restrict__ out){
  __shared__ float s0[1600], s1[1600];
  size_t base = (size_t)blockIdx.x * 1600;
  int t = threadIdx.x;
  for (int e = t; e < 1600; e += 256) s0[e] = in[base + e];
  __syncthreads();
  for (int e = t; e < 1600; e += 256){
    int w = e % 40;
    float s = s0[e];
    if (w > 0)  s += s0[e - 1];
    if (w < 39) s += s0[e + 1];
    s1[e] = s;
  }
  __syncthreads();
  for (int e = t; e < 1600; e += 256){
    int h = e / 40;
    float s = s1[e];
    if (h > 0)  s += s1[e - 40];
    if (h < 39) s += s1[e + 40];
    out[base + e] = s;
  }
}
__global__ void boxd_k(const float* __restrict__ in, float* __restrict__ out){
  int g = blockIdx.x * 256 + threadIdx.x;
  int d = (g / 1600) % 40;
  float s = in[g];
  if (d > 0)  s += in[g - 1600];
  if (d < 39) s += in[g + 1600];
  out[g] = s * (1.f / 27.f);
}

// ---------------- transpose xm [c][n] -> xmt [n][c] (LDS 64x64 tiles)
// + zeroes the KM accumulator region; block 0 seeds kmeans iter0 bank0.
__global__ __launch_bounds__(256) void transp_k(const float* __restrict__ in,
                                                float* __restrict__ out,
                                                float* __restrict__ km){
  __shared__ float tile[64][65];
  int t = threadIdx.x;
  int nb = blockIdx.x * 64;
  int l = t & 63, g = t >> 6;
  for (int j = 260 + blockIdx.x * 256 + t; j < 11 * ITST; j += 1000 * 256)
    km[j] = 0.f;
  for (int cc = g; cc < 64; cc += 4)
    tile[cc][l] = in[(size_t)cc * NVOX + nb + l];
  __syncthreads();
  if (blockIdx.x == 0){
    km[t] = tile[t & 63][t >> 6];
    if (t < 4) km[256 + t] = 1.f;
  }
  for (int nn = g; nn < 64; nn += 4)
    out[(size_t)(nb + nn) * 64 + l] = tile[l][nn];
}

// ---------------- kmeans assign + reduce (mode 0) or idx write + MLPs (mode 1)
__global__ __launch_bounds__(256) void assign_k(const float* __restrict__ xmt,
                                                const float* __restrict__ kin,
                                                float* __restrict__ kout,
                                                int* __restrict__ idx, int mode,
                      const float* __restrict__ w1, const float* __restrict__ b1,
                      const float* __restrict__ w2, const float* __restrict__ b2,
                      const float* __restrict__ w3, const float* __restrict__ b3,
                      const float* __restrict__ u1, const float* __restrict__ c1,
                      const float* __restrict__ u2, const float* __restrict__ c2,
                      const float* __restrict__ u3, const float* __restrict__ c3,
                      float* __restrict__ wi, float* __restrict__ bias){
  __shared__ float s_cent[256];
  __shared__ float s_cc[4];
  __shared__ float s_red[260];
  __shared__ float s_x[256 * 65];
  __shared__ int   s_kb[256];
  __shared__ float s_h1[128], s_h2[128], s_g1[64], s_g2[64];
  int t = threadIdx.x, lane = t & 63, wv = t >> 6;
  int n = blockIdx.x * 256 + t;
  {
    float sum = 0.f, cnt = 0.f;
#pragma unroll
    for (int s = 0; s < NCPY; s++){
      sum += kin[s * 260 + t];
      cnt += kin[s * 260 + 256 + (t >> 6)];
    }
    s_cent[t] = sum / fmaxf(cnt, 1.f);
  }
  for (int j = t; j < 260; j += 256) s_red[j] = 0.f;
  __syncthreads();
  if (t < 4){
    const float4* cc4 = (const float4*)(s_cent + t * 64);
    float s = 0.f;
#pragma unroll
    for (int q = 0; q < 16; q++){
      float4 v = cc4[q];
      s = fmaf(v.x, v.x, s); s = fmaf(v.y, v.y, s);
      s = fmaf(v.z, v.z, s); s = fmaf(v.w, v.w, s);
    }
    s_cc[t] = s;
  }
  __syncthreads();
  const float4* xt = (const float4*)(xmt + (size_t)n * 64);
  float4 xq[16];
#pragma unroll
  for (int q = 0; q < 16; q++) xq[q] = xt[q];
  float d0 = 0.f, d1 = 0.f, d2 = 0.f, d3 = 0.f;
  const float4* c4 = (const float4*)s_cent;
#pragma unroll
  for (int q = 0; q < 16; q++){
    float4 p0 = c4[q], p1 = c4[16 + q], p2 = c4[32 + q], p3 = c4[48 + q];
    d0 = fmaf(p0.x, xq[q].x, d0); d0 = fmaf(p0.y, xq[q].y, d0);
    d0 = fmaf(p0.z, xq[q].z, d0); d0 = fmaf(p0.w, xq[q].w, d0);
    d1 = fmaf(p1.x, xq[q].x, d1); d1 = fmaf(p1.y, xq[q].y, d1);
    d1 = fmaf(p1.z, xq[q].z, d1); d1 = fmaf(p1.w, xq[q].w, d1);
    d2 = fmaf(p2.x, xq[q].x, d2); d2 = fmaf(p2.y, xq[q].y, d2);
    d2 = fmaf(p2.z, xq[q].z, d2); d2 = fmaf(p2.w, xq[q].w, d2);
    d3 = fmaf(p3.x, xq[q].x, d3); d3 = fmaf(p3.y, xq[q].y, d3);
    d3 = fmaf(p3.z, xq[q].z, d3); d3 = fmaf(p3.w, xq[q].w, d3);
  }
  float sc0 = s_cc[0] - 2.f * d0;
  float sc1 = s_cc[1] - 2.f * d1;
  float sc2 = s_cc[2] - 2.f * d2;
  float sc3 = s_cc[3] - 2.f * d3;
  int kb = 0; float bs = sc0;
  if (sc1 < bs){ bs = sc1; kb = 1; }
  if (sc2 < bs){ bs = sc2; kb = 2; }
  if (sc3 < bs){ bs = sc3; kb = 3; }
  if (mode){
    idx[n] = kb;
    if (blockIdx.x == 0){
      __syncthreads();
      if (t < 128){
        float z = b1[t];
        for (int i = 0; i < 256; i++) z = fmaf(s_cent[i], w1[i * 128 + t], z);
        s_h1[t] = fmaxf(z, 0.f);
      }
      if (t < 64){
        float z = c1[t];
        for (int i = 0; i < 256; i++) z = fmaf(s_cent[i], u1[i * 64 + t], z);
        s_g1[t] = fmaxf(z, 0.f);
      }
      __syncthreads();
      if (t < 128){
        float z = b2[t];
        for (int i = 0; i < 128; i++) z = fmaf(s_h1[i], w2[i * 128 + t], z);
        s_h2[t] = fmaxf(z, 0.f);
      }
      if (t < 64){
        float z = c2[t];
        for (int i = 0; i < 64; i++) z = fmaf(s_g1[i], u2[i * 64 + t], z);
        s_g2[t] = fmaxf(z, 0.f);
      }
      __syncthreads();
      if (t < 108){
        float z = b3[t];
        for (int i = 0; i < 128; i++) z = fmaf(s_h2[i], w3[i * 108 + t], z);
        wi[t] = 1.f / (1.f + expf(-z));
      }
      {
        float z = c3[t];
        for (int i = 0; i < 64; i++) z = fmaf(s_g2[i], u3[i * 256 + t], z);
        bias[t] = z;
      }
    }
    return;
  }
  s_kb[t] = kb;
#pragma unroll
  for (int q = 0; q < 16; q++){
    s_x[t * 65 + 4*q + 0] = xq[q].x;
    s_x[t * 65 + 4*q + 1] = xq[q].y;
    s_x[t * 65 + 4*q + 2] = xq[q].z;
    s_x[t * 65 + 4*q + 3] = xq[q].w;
  }
  __syncthreads();
  float a0 = 0.f, a1 = 0.f, a2 = 0.f, a3 = 0.f;
  int rowbase = wv * 64;
#pragma unroll 16
  for (int j = 0; j < 64; j++){
    float v = s_x[(rowbase + j) * 65 + lane];
    int kj = s_kb[rowbase + j];
    a0 += (kj == 0) ? v : 0.f;
    a1 += (kj == 1) ? v : 0.f;
    a2 += (kj == 2) ? v : 0.f;
    a3 += (kj == 3) ? v : 0.f;
  }
  atomicAdd(&s_red[lane], a0);
  atomicAdd(&s_red[64 + lane], a1);
  atomicAdd(&s_red[128 + lane], a2);
  atomicAdd(&s_red[192 + lane], a3);
#pragma unroll
  for (int kk = 0; kk < 4; kk++){
    unsigned long long m = __ballot(kb == kk);
    if (lane == 0) atomicAdd(&s_red[256 + kk], (float)__popcll(m));
  }
  __syncthreads();
  float* kslot = kout + (blockIdx.x & (NCPY - 1)) * 260;
  for (int j = t; j < 260; j += 256) atomicAdd(&kslot[j], s_red[j]);
}

// ---------------- main dynamic conv: grid (1000, 2). blockIdx.y = output-ch
// half (oh*32..+31). R6 measured 49us @31% occupancy (15.6 waves/CU); 2000
// blocks -> 31 waves/CU. Same proven 4-wave kc-pair reduction; per wave:
// 2 col-tiles (nh) x 2 o-subtiles (a0/a1). b/idx reads duplicate x2 (L2-hot).
__global__ __launch_bounds__(256) void conv_k(const short* __restrict__ xpt,
                                              const short* __restrict__ bwb,
                                              const float* __restrict__ wi,
                                              const float* __restrict__ bias,
                                              const int* __restrict__ idx,
                                              const float* __restrict__ x,
                                              const float* __restrict__ pa,
                                              float* __restrict__ out){
  static const int POFF[27] = {
    -P2-42-1, -P2-42, -P2-42+1, -P2-1, -P2, -P2+1, -P2+42-1, -P2+42, -P2+42+1,
    -42-1, -42, -42+1, -1, 0, 1, 42-1, 42, 42+1,
    P2-42-1, P2-42, P2-42+1, P2-1, P2, P2+1, P2+42-1, P2+42, P2+42+1 };
  __shared__ float s_wi[108];
  __shared__ float s_bias[256];
  __shared__ float s_acc[64 * 36];
  int tid = threadIdx.x;
  for (int j = tid; j < 108; j += 256) s_wi[j] = wi[j];
  s_bias[tid] = bias[tid];
  __syncthreads();
  int wv = tid >> 6, lane = tid & 63;
  int kc = wv & 1, nh = wv >> 1;
  int oh = blockIdx.y;
  int col = lane & 15, kg = lane >> 4;
  int vb = blockIdx.x * 64;
  int p4[2], ki4[2];
#pragma unroll
  for (int j = 0; j < 2; j++){
    int v = vb + (nh * 2 + j) * 16 + col;
    ki4[j] = idx[v];
    int d = v / 1600; int r = v - d * 1600; int h = r / 40; int w = r - h * 40;
    p4[j] = ((d + 1) * 42 + (h + 1)) * 42 + (w + 1);
  }
  const short* bg = xpt + (size_t)(kc * 4 + kg) * GSTR;
  const short* bp0 = bg + (size_t)p4[0] * 8;
  const short* bp1 = bg + (size_t)p4[1] * 8;
  int ao0 = (oh * 32 + col) * 64 + kc * 32 + kg * 8;
  int ao1 = ao0 + 16 * 64;
  v4f acc[2][2];
#pragma unroll
  for (int m2 = 0; m2 < 2; m2++)
#pragma unroll
    for (int j = 0; j < 2; j++) acc[m2][j] = (v4f){0.f, 0.f, 0.f, 0.f};
  v4f zero = {0.f, 0.f, 0.f, 0.f};
#pragma unroll 9
  for (int t = 0; t < 27; t++){
    int po8 = POFF[t] * 8;
    v8s a0 = *(const v8s*)(bwb + t * 4096 + ao0);
    v8s a1 = *(const v8s*)(bwb + t * 4096 + ao1);
    v8s b0 = *(const v8s*)(bp0 + po8);
    v8s b1 = *(const v8s*)(bp1 + po8);
    float wk0 = s_wi[ki4[0] * 27 + t];
    float wk1 = s_wi[ki4[1] * 27 + t];
    v4f tp;
    tp = __builtin_amdgcn_mfma_f32_16x16x32_bf16(a0, b0, zero, 0, 0, 0); acc[0][0] += tp * wk0;
    tp = __builtin_amdgcn_mfma_f32_16x16x32_bf16(a1, b0, zero, 0, 0, 0); acc[1][0] += tp * wk0;
    tp = __builtin_amdgcn_mfma_f32_16x16x32_bf16(a0, b1, zero, 0, 0, 0); acc[0][1] += tp * wk1;
    tp = __builtin_amdgcn_mfma_f32_16x16x32_bf16(a1, b1, zero, 0, 0, 0); acc[1][1] += tp * wk1;
  }
  __syncthreads();
  if (kc == 1){
#pragma unroll
    for (int m2 = 0; m2 < 2; m2++)
#pragma unroll
      for (int j = 0; j < 2; j++)
        *(v4f*)(&s_acc[((nh * 2 + j) * 16 + col) * 36 + m2 * 16 + kg * 4]) = acc[m2][j];
  }
  __syncthreads();
  if (kc == 0){
    float pav = pa[0];
#pragma unroll
    for (int m2 = 0; m2 < 2; m2++){
#pragma unroll
      for (int j = 0; j < 2; j++){
        v4f other = *(const v4f*)(&s_acc[((nh * 2 + j) * 16 + col) * 36 + m2 * 16 + kg * 4]);
        v4f sum = acc[m2][j] + other;
        int n = vb + (nh * 2 + j) * 16 + col;
#pragma unroll
        for (int r = 0; r < 4; r++){
          int o = oh * 32 + m2 * 16 + kg * 4 + r;
          float val = sum[r] + s_bias[ki4[j] * 64 + o];
          val = (val >= 0.f) ? val : pav * val;
          size_t off = (size_t)o * NVOX + n;
          out[off] = val + x[off];
        }
      }
    }
  }
}

extern "C" void kernel_launch(void* const* d_in, const int* in_sizes, int n_in,
                              void* d_out, int out_size, void* d_ws, size_t ws_size,
                              hipStream_t stream){
  const float* x    = (const float*)d_in[0];
  const float* pw   = (const float*)d_in[1];
  const float* bw   = (const float*)d_in[2];
  const float* gkw1 = (const float*)d_in[3];
  const float* gkb1 = (const float*)d_in[4];
  const float* gkw2 = (const float*)d_in[5];
  const float* gkb2 = (const float*)d_in[6];
  const float* gkw3 = (const float*)d_in[7];
  const float* gkb3 = (const float*)d_in[8];
  const float* gbw1 = (const float*)d_in[9];
  const float* gbb1 = (const float*)d_in[10];
  const float* gbw2 = (const float*)d_in[11];
  const float* gbb2 = (const float*)d_in[12];
  const float* gbw3 = (const float*)d_in[13];
  const float* gbb3 = (const float*)d_in[14];
  const float* pa   = (const float*)d_in[15];
  float* outp = (float*)d_out;

  float* ws   = (float*)d_ws;
  float* XP   = ws;                                  // 4,096,000 f ; reused as XMT
  float* BU2  = ws + 4096000;                        // 4,096,000 f
  float* BU1  = ws + 8192000;                        // 4,096,000 f (xm [c][n])
  short* XPT  = (short*)(ws + 12288000);             // 4,741,632 s
  short* BWB  = XPT + (size_t)NPAD * 64;             // 110,592 s
  float* KM   = (float*)(BWB + 110592);              // 11*8320 f
  float* WI   = KM + 11 * ITST;                      // 108 f
  float* BIAS = WI + 108;                            // 256 f
  int*   IDX  = (int*)(BIAS + 256);                  // 64,000 i
  float* XMT  = XP;                                  // xm transposed [n][c]

  prep_k<<<1472, 256, 0, stream>>>(x, pw, XP, XPT, bw, BWB);
  boxwh_k<<<2560, 256, 0, stream>>>(XP, BU2);
  boxd_k<<<16000, 256, 0, stream>>>(BU2, BU1);
  transp_k<<<1000, 256, 0, stream>>>(BU1, XMT, KM);
  for (int i = 0; i <= 10; i++)
    assign_k<<<250, 256, 0, stream>>>(XMT, KM + i * ITST, KM + (i + 1) * ITST, IDX,
                                      (i == 10) ? 1 : 0,
                                      gkw1, gkb1, gkw2, gkb2, gkw3, gkb3,
                                      gbw1, gbb1, gbw2, gbb2, gbw3, gbb3,
                                      WI, BIAS);
  conv_k<<<dim3(1000, 2), 256, 0, stream>>>(XPT, BWB, WI, BIAS, IDX, x, pa, outp);
}

// Round 10
// 338.244 us; speedup vs baseline: 1.0297x; 1.0297x over previous
//
#include <hip/hip_runtime.h>
#include <math.h>

typedef short v8s __attribute__((ext_vector_type(8)));
typedef float v4f __attribute__((ext_vector_type(4)));

#define NVOX 64000      // 40^3
#define NPAD 74088      // 42^3
#define P2   1764       // 42^2
#define GSTR 592704     // NPAD*8
#define NCPY 32         // banked global-accumulator copies
#define ITST (NCPY*260) // stride per kmeans iteration (8320 floats)

__device__ __forceinline__ unsigned short bf16rne(float f){
  unsigned int u = __float_as_uint(f);
  u += 0x7FFFu + ((u >> 16) & 1u);
  return (unsigned short)(u >> 16);
}

// ---------------- merged prep: projection (blocks 0..999, 4-way channel split)
// + base_w bf16 repack (1000..1431) + xpt halo zeroing (1432..1471)
// + KM accumulator zeroing (1472..1553) (must precede boxdt's atomic flush).
__global__ __launch_bounds__(256) void prep_k(const float* __restrict__ x,
                                              const float* __restrict__ pw,
                                              float* __restrict__ xp,
                                              short* __restrict__ xpt,
                                              const float* __restrict__ bw,
                                              short* __restrict__ bwb,
                                              float* __restrict__ km){
  int tid = threadIdx.x;
  int bid = blockIdx.x;
  if (bid < 1000){
    int m = (bid >> 2) * 256 + tid;
    int quarter = bid & 3;
    float xv[64];
#pragma unroll
    for (int i = 0; i < 64; i++) xv[i] = x[(size_t)i * NVOX + m];
    int d = m / 1600; int r = m - d * 1600; int h = r / 40; int w = r - h * 40;
    int p = ((d + 1) * 42 + (h + 1)) * 42 + (w + 1);
    const float4* pw4 = (const float4*)pw;
    for (int g8 = quarter * 2; g8 < quarter * 2 + 2; g8++){
      v8s pk;
#pragma unroll
      for (int j = 0; j < 8; j++){
        int co = g8 * 8 + j;
        float acc = 0.f;
#pragma unroll
        for (int q = 0; q < 16; q++){
          float4 pv = pw4[co * 16 + q];   // wave-uniform -> scalar K$ loads
          acc = fmaf(pv.x, xv[4*q+0], acc);
          acc = fmaf(pv.y, xv[4*q+1], acc);
          acc = fmaf(pv.z, xv[4*q+2], acc);
          acc = fmaf(pv.w, xv[4*q+3], acc);
        }
        xp[(size_t)co * NVOX + m] = acc;
        pk[j] = (short)bf16rne(acc);
      }
      *(v8s*)(xpt + (size_t)g8 * GSTR + (size_t)p * 8) = pk;
    }
  } else if (bid < 1432){
    int e = (bid - 1000) * 256 + tid;               // 0 .. 110591
    int t5 = e >> 12; int rem = e & 4095;
    int o = rem >> 6; int c = rem & 63;
    bwb[e] = (short)bf16rne(bw[(o * 64 + c) * 27 + t5]);
  } else if (bid < 1472){
    v8s z = (v8s){0,0,0,0,0,0,0,0};
    for (int p = (bid - 1432) * 256 + tid; p < NPAD; p += 40 * 256){
      int d = p / P2; int rem = p - d * P2; int h = rem / 42; int w = rem - h * 42;
      if (d == 0 || d == 41 || h == 0 || h == 41 || w == 0 || w == 41){
#pragma unroll
        for (int g = 0; g < 8; g++)
          *(v8s*)(xpt + (size_t)g * GSTR + (size_t)p * 8) = z;
      }
    }
  } else {
    for (int j = (bid - 1472) * 256 + tid; j < 10 * ITST; j += 82 * 256)
      km[j] = 0.f;
  }
}

// ---------------- fused w+h box passes per (c,d) slice (zero pad) — R6-proven
__global__ __launch_bounds__(256) void boxwh_k(const float* __restrict__ in,
                                               float* __restrict__ out){
  __shared__ float s0[1600], s1[1600];
  size_t base = (size_t)blockIdx.x * 1600;
  int t = threadIdx.x;
  for (int e = t; e < 1600; e += 256) s0[e] = in[base + e];
  __syncthreads();
  for (int e = t; e < 1600; e += 256){
    int w = e % 40;
    float s = s0[e];
    if (w > 0)  s += s0[e - 1];
    if (w < 39) s += s0[e + 1];
    s1[e] = s;
  }
  __syncthreads();
  for (int e = t; e < 1600; e += 256){
    int h = e / 40;
    float s = s1[e];
    if (h > 0)  s += s1[e - 40];
    if (h < 39) s += s1[e + 40];
    out[base + e] = s;
  }
}

// ---------------- fused boxd + transpose + kmeans-iter0.
// Block = 64-voxel n-tile. tile[c][l] = xm[c][nb+l] computed on the fly from
// the wh-filtered field (3 shifted reads). cent0 = xm at n=0..3, computed by
// every block from 512 broadcast loads. Assigns its 64 points vs cent0 and
// flushes banked partial sums (= old assign iter-0 output) to acc1; writes
// XMT transpose. Replaces boxd_k + transp_k + one assign_k launch.
__global__ __launch_bounds__(256) void boxdt_k(const float* __restrict__ in,
                                               float* __restrict__ out,
                                               float* __restrict__ acc1){
  __shared__ float tile[64][65];
  __shared__ float s_cent[256];
  __shared__ float s_cc[4];
  __shared__ float s_red[260];
  __shared__ int   s_kb[64];
  int t = threadIdx.x;
  int nb = blockIdx.x * 64;
  int l = t & 63, g = t >> 6;
  {
    int k = t >> 6, c = t & 63;   // cent0[k][c] = (BU2[c][k] + BU2[c][k+1600])/27 (d=0)
    s_cent[t] = (in[(size_t)c * NVOX + k] + in[(size_t)c * NVOX + k + 1600]) * (1.f / 27.f);
  }
  for (int j = t; j < 260; j += 256) s_red[j] = 0.f;
  int n = nb + l;
  int d = n / 1600;
  for (int cc = g; cc < 64; cc += 4){
    const float* b = in + (size_t)cc * NVOX + n;
    float s = b[0];
    if (d > 0)  s += b[-1600];
    if (d < 39) s += b[1600];
    tile[cc][l] = s * (1.f / 27.f);
  }
  __syncthreads();
  if (t < 4){
    float s = 0.f;
    for (int c = 0; c < 64; c++){ float v = s_cent[t * 64 + c]; s = fmaf(v, v, s); }
    s_cc[t] = s;
  }
  __syncthreads();
  if (t < 64){
    float d0 = 0.f, d1 = 0.f, d2 = 0.f, d3 = 0.f;
    for (int c = 0; c < 64; c++){
      float v = tile[c][t];
      d0 = fmaf(s_cent[c], v, d0);
      d1 = fmaf(s_cent[64 + c], v, d1);
      d2 = fmaf(s_cent[128 + c], v, d2);
      d3 = fmaf(s_cent[192 + c], v, d3);
    }
    float sc0 = s_cc[0] - 2.f * d0;
    float sc1 = s_cc[1] - 2.f * d1;
    float sc2 = s_cc[2] - 2.f * d2;
    float sc3 = s_cc[3] - 2.f * d3;
    int kb = 0; float bs = sc0;
    if (sc1 < bs){ bs = sc1; kb = 1; }
    if (sc2 < bs){ bs = sc2; kb = 2; }
    if (sc3 < bs){ bs = sc3; kb = 3; }
    s_kb[t] = kb;
  }
  __syncthreads();
  {
    int lane = t & 63, wv = t >> 6;
    float a0 = 0.f, a1 = 0.f, a2 = 0.f, a3 = 0.f;
#pragma unroll
    for (int j = 0; j < 16; j++){
      int p = wv * 16 + j;
      float v = tile[lane][p];
      int kj = s_kb[p];
      a0 += (kj == 0) ? v : 0.f;
      a1 += (kj == 1) ? v : 0.f;
      a2 += (kj == 2) ? v : 0.f;
      a3 += (kj == 3) ? v : 0.f;
    }
    atomicAdd(&s_red[lane], a0);
    atomicAdd(&s_red[64 + lane], a1);
    atomicAdd(&s_red[128 + lane], a2);
    atomicAdd(&s_red[192 + lane], a3);
  }
  if (t < 4){
    float c = 0.f;
    for (int p = 0; p < 64; p++) c += (s_kb[p] == t) ? 1.f : 0.f;
    s_red[256 + t] = c;     // single writer per slot
  }
  __syncthreads();
  float* kslot = acc1 + (blockIdx.x & (NCPY - 1)) * 260;
  for (int j = t; j < 260; j += 256) atomicAdd(&kslot[j], s_red[j]);
  for (int nn = g; nn < 64; nn += 4)
    out[(size_t)(nb + nn) * 64 + l] = tile[l][nn];
}

// ---------------- kmeans assign + reduce (mode 0) or idx write + MLPs (mode 1)
__global__ __launch_bounds__(256) void assign_k(const float* __restrict__ xmt,
                                                const float* __restrict__ kin,
                                                float* __restrict__ kout,
                                                int* __restrict__ idx, int mode,
                      const float* __restrict__ w1, const float* __restrict__ b1,
                      const float* __restrict__ w2, const float* __restrict__ b2,
                      const float* __restrict__ w3, const float* __restrict__ b3,
                      const float* __restrict__ u1, const float* __restrict__ c1,
                      const float* __restrict__ u2, const float* __restrict__ c2,
                      const float* __restrict__ u3, const float* __restrict__ c3,
                      float* __restrict__ wi, float* __restrict__ bias){
  __shared__ float s_cent[256];
  __shared__ float s_cc[4];
  __shared__ float s_red[260];
  __shared__ float s_x[256 * 65];
  __shared__ int   s_kb[256];
  __shared__ float s_h1[128], s_h2[128], s_g1[64], s_g2[64];
  int t = threadIdx.x, lane = t & 63, wv = t >> 6;
  int n = blockIdx.x * 256 + t;
  {
    float sum = 0.f, cnt = 0.f;
#pragma unroll
    for (int s = 0; s < NCPY; s++){
      sum += kin[s * 260 + t];
      cnt += kin[s * 260 + 256 + (t >> 6)];
    }
    s_cent[t] = sum / fmaxf(cnt, 1.f);
  }
  for (int j = t; j < 260; j += 256) s_red[j] = 0.f;
  __syncthreads();
  if (t < 4){
    const float4* cc4 = (const float4*)(s_cent + t * 64);
    float s = 0.f;
#pragma unroll
    for (int q = 0; q < 16; q++){
      float4 v = cc4[q];
      s = fmaf(v.x, v.x, s); s = fmaf(v.y, v.y, s);
      s = fmaf(v.z, v.z, s); s = fmaf(v.w, v.w, s);
    }
    s_cc[t] = s;
  }
  __syncthreads();
  const float4* xt = (const float4*)(xmt + (size_t)n * 64);
  float4 xq[16];
#pragma unroll
  for (int q = 0; q < 16; q++) xq[q] = xt[q];
  float d0 = 0.f, d1 = 0.f, d2 = 0.f, d3 = 0.f;
  const float4* c4 = (const float4*)s_cent;
#pragma unroll
  for (int q = 0; q < 16; q++){
    float4 p0 = c4[q], p1 = c4[16 + q], p2 = c4[32 + q], p3 = c4[48 + q];
    d0 = fmaf(p0.x, xq[q].x, d0); d0 = fmaf(p0.y, xq[q].y, d0);
    d0 = fmaf(p0.z, xq[q].z, d0); d0 = fmaf(p0.w, xq[q].w, d0);
    d1 = fmaf(p1.x, xq[q].x, d1); d1 = fmaf(p1.y, xq[q].y, d1);
    d1 = fmaf(p1.z, xq[q].z, d1); d1 = fmaf(p1.w, xq[q].w, d1);
    d2 = fmaf(p2.x, xq[q].x, d2); d2 = fmaf(p2.y, xq[q].y, d2);
    d2 = fmaf(p2.z, xq[q].z, d2); d2 = fmaf(p2.w, xq[q].w, d2);
    d3 = fmaf(p3.x, xq[q].x, d3); d3 = fmaf(p3.y, xq[q].y, d3);
    d3 = fmaf(p3.z, xq[q].z, d3); d3 = fmaf(p3.w, xq[q].w, d3);
  }
  float sc0 = s_cc[0] - 2.f * d0;
  float sc1 = s_cc[1] - 2.f * d1;
  float sc2 = s_cc[2] - 2.f * d2;
  float sc3 = s_cc[3] - 2.f * d3;
  int kb = 0; float bs = sc0;
  if (sc1 < bs){ bs = sc1; kb = 1; }
  if (sc2 < bs){ bs = sc2; kb = 2; }
  if (sc3 < bs){ bs = sc3; kb = 3; }
  if (mode){
    idx[n] = kb;
    if (blockIdx.x == 0){
      __syncthreads();
      if (t < 128){
        float z = b1[t];
        for (int i = 0; i < 256; i++) z = fmaf(s_cent[i], w1[i * 128 + t], z);
        s_h1[t] = fmaxf(z, 0.f);
      }
      if (t < 64){
        float z = c1[t];
        for (int i = 0; i < 256; i++) z = fmaf(s_cent[i], u1[i * 64 + t], z);
        s_g1[t] = fmaxf(z, 0.f);
      }
      __syncthreads();
      if (t < 128){
        float z = b2[t];
        for (int i = 0; i < 128; i++) z = fmaf(s_h1[i], w2[i * 128 + t], z);
        s_h2[t] = fmaxf(z, 0.f);
      }
      if (t < 64){
        float z = c2[t];
        for (int i = 0; i < 64; i++) z = fmaf(s_g1[i], u2[i * 64 + t], z);
        s_g2[t] = fmaxf(z, 0.f);
      }
      __syncthreads();
      if (t < 108){
        float z = b3[t];
        for (int i = 0; i < 128; i++) z = fmaf(s_h2[i], w3[i * 108 + t], z);
        wi[t] = 1.f / (1.f + expf(-z));
      }
      {
        float z = c3[t];
        for (int i = 0; i < 64; i++) z = fmaf(s_g2[i], u3[i * 256 + t], z);
        bias[t] = z;
      }
    }
    return;
  }
  s_kb[t] = kb;
#pragma unroll
  for (int q = 0; q < 16; q++){
    s_x[t * 65 + 4*q + 0] = xq[q].x;
    s_x[t * 65 + 4*q + 1] = xq[q].y;
    s_x[t * 65 + 4*q + 2] = xq[q].z;
    s_x[t * 65 + 4*q + 3] = xq[q].w;
  }
  __syncthreads();
  float a0 = 0.f, a1 = 0.f, a2 = 0.f, a3 = 0.f;
  int rowbase = wv * 64;
#pragma unroll 16
  for (int j = 0; j < 64; j++){
    float v = s_x[(rowbase + j) * 65 + lane];
    int kj = s_kb[rowbase + j];
    a0 += (kj == 0) ? v : 0.f;
    a1 += (kj == 1) ? v : 0.f;
    a2 += (kj == 2) ? v : 0.f;
    a3 += (kj == 3) ? v : 0.f;
  }
  atomicAdd(&s_red[lane], a0);
  atomicAdd(&s_red[64 + lane], a1);
  atomicAdd(&s_red[128 + lane], a2);
  atomicAdd(&s_red[192 + lane], a3);
#pragma unroll
  for (int kk = 0; kk < 4; kk++){
    unsigned long long m = __ballot(kb == kk);
    if (lane == 0) atomicAdd(&s_red[256 + kk], (float)__popcll(m));
  }
  __syncthreads();
  float* kslot = kout + (blockIdx.x & (NCPY - 1)) * 260;
  for (int j = t; j < 260; j += 256) atomicAdd(&kslot[j], s_red[j]);
}

// ---------------- main dynamic conv: n-split. Grid 2000, vb = bid*32, 2
// col-tiles per wave (was 4). Wave roles (kc,mh), fragment layout, s_acc
// exchange identical to the R6-proven kernel; xpt gathers stay DISJOINT
// across blocks (R9 showed o-split duplication re-fetches from HBM).
__global__ __launch_bounds__(256) void conv_k(const short* __restrict__ xpt,
                                              const short* __restrict__ bwb,
                                              const float* __restrict__ wi,
                                              const float* __restrict__ bias,
                                              const int* __restrict__ idx,
                                              const float* __restrict__ x,
                                              const float* __restrict__ pa,
                                              float* __restrict__ out){
  static const int POFF[27] = {
    -P2-42-1, -P2-42, -P2-42+1, -P2-1, -P2, -P2+1, -P2+42-1, -P2+42, -P2+42+1,
    -42-1, -42, -42+1, -1, 0, 1, 42-1, 42, 42+1,
    P2-42-1, P2-42, P2-42+1, P2-1, P2, P2+1, P2+42-1, P2+42, P2+42+1 };
  __shared__ float s_wi[108];
  __shared__ float s_bias[256];
  __shared__ float s_acc[32 * 68];
  int tid = threadIdx.x;
  for (int j = tid; j < 108; j += 256) s_wi[j] = wi[j];
  s_bias[tid] = bias[tid];
  __syncthreads();
  int wv = tid >> 6, lane = tid & 63;
  int kc = wv & 1, mh = wv >> 1;
  int col = lane & 15, kg = lane >> 4;
  int vb = blockIdx.x * 32;
  int p4[2], ki4[2];
#pragma unroll
  for (int nt = 0; nt < 2; nt++){
    int v = vb + nt * 16 + col;
    ki4[nt] = idx[v];
    int d = v / 1600; int r = v - d * 1600; int h = r / 40; int w = r - h * 40;
    p4[nt] = ((d + 1) * 42 + (h + 1)) * 42 + (w + 1);
  }
  const short* bg = xpt + (size_t)(kc * 4 + kg) * GSTR;
  const short* bp0 = bg + (size_t)p4[0] * 8;
  const short* bp1 = bg + (size_t)p4[1] * 8;
  int ao0 = (mh * 32 + col) * 64 + kc * 32 + kg * 8;
  int ao1 = ao0 + 16 * 64;
  v4f acc[2][2];
#pragma unroll
  for (int m2 = 0; m2 < 2; m2++)
#pragma unroll
    for (int nt = 0; nt < 2; nt++) acc[m2][nt] = (v4f){0.f, 0.f, 0.f, 0.f};
  v4f zero = {0.f, 0.f, 0.f, 0.f};
#pragma unroll 9
  for (int t = 0; t < 27; t++){
    int po8 = POFF[t] * 8;
    v8s a0 = *(const v8s*)(bwb + t * 4096 + ao0);
    v8s a1 = *(const v8s*)(bwb + t * 4096 + ao1);
    v8s b0 = *(const v8s*)(bp0 + po8);
    v8s b1 = *(const v8s*)(bp1 + po8);
    float wk0 = s_wi[ki4[0] * 27 + t];
    float wk1 = s_wi[ki4[1] * 27 + t];
    v4f tp;
    tp = __builtin_amdgcn_mfma_f32_16x16x32_bf16(a0, b0, zero, 0, 0, 0); acc[0][0] += tp * wk0;
    tp = __builtin_amdgcn_mfma_f32_16x16x32_bf16(a1, b0, zero, 0, 0, 0); acc[1][0] += tp * wk0;
    tp = __builtin_amdgcn_mfma_f32_16x16x32_bf16(a0, b1, zero, 0, 0, 0); acc[0][1] += tp * wk1;
    tp = __builtin_amdgcn_mfma_f32_16x16x32_bf16(a1, b1, zero, 0, 0, 0); acc[1][1] += tp * wk1;
  }
  __syncthreads();
  if (kc == 1){
#pragma unroll
    for (int m2 = 0; m2 < 2; m2++)
#pragma unroll
      for (int nt = 0; nt < 2; nt++)
        *(v4f*)(&s_acc[(nt * 16 + col) * 68 + mh * 32 + m2 * 16 + kg * 4]) = acc[m2][nt];
  }
  __syncthreads();
  if (kc == 0){
    float pav = pa[0];
#pragma unroll
    for (int m2 = 0; m2 < 2; m2++){
#pragma unroll
      for (int nt = 0; nt < 2; nt++){
        v4f other = *(const v4f*)(&s_acc[(nt * 16 + col) * 68 + mh * 32 + m2 * 16 + kg * 4]);
        v4f sum = acc[m2][nt] + other;
        int n = vb + nt * 16 + col;
#pragma unroll
        for (int r = 0; r < 4; r++){
          int o = mh * 32 + m2 * 16 + kg * 4 + r;
          float val = sum[r] + s_bias[ki4[nt] * 64 + o];
          val = (val >= 0.f) ? val : pav * val;
          size_t off = (size_t)o * NVOX + n;
          out[off] = val + x[off];
        }
      }
    }
  }
}

extern "C" void kernel_launch(void* const* d_in, const int* in_sizes, int n_in,
                              void* d_out, int out_size, void* d_ws, size_t ws_size,
                              hipStream_t stream){
  const float* x    = (const float*)d_in[0];
  const float* pw   = (const float*)d_in[1];
  const float* bw   = (const float*)d_in[2];
  const float* gkw1 = (const float*)d_in[3];
  const float* gkb1 = (const float*)d_in[4];
  const float* gkw2 = (const float*)d_in[5];
  const float* gkb2 = (const float*)d_in[6];
  const float* gkw3 = (const float*)d_in[7];
  const float* gkb3 = (const float*)d_in[8];
  const float* gbw1 = (const float*)d_in[9];
  const float* gbb1 = (const float*)d_in[10];
  const float* gbw2 = (const float*)d_in[11];
  const float* gbb2 = (const float*)d_in[12];
  const float* gbw3 = (const float*)d_in[13];
  const float* gbb3 = (const float*)d_in[14];
  const float* pa   = (const float*)d_in[15];
  float* outp = (float*)d_out;

  float* ws   = (float*)d_ws;
  float* XP   = ws;                                  // 4,096,000 f ; reused as XMT
  float* BU2  = ws + 4096000;                        // 4,096,000 f (wh-filtered)
  short* XPT  = (short*)(ws + 12288000);             // 4,741,632 s
  short* BWB  = XPT + (size_t)NPAD * 64;             // 110,592 s
  float* KM   = (float*)(BWB + 110592);              // 10*8320 f  (ACC[1..10])
  float* WI   = KM + 10 * ITST;                      // 108 f
  float* BIAS = WI + 108;                            // 256 f
  int*   IDX  = (int*)(BIAS + 256);                  // 64,000 i
  float* XMT  = XP;                                  // xm transposed [n][c]

  prep_k<<<1554, 256, 0, stream>>>(x, pw, XP, XPT, bw, BWB, KM);
  boxwh_k<<<2560, 256, 0, stream>>>(XP, BU2);
  boxdt_k<<<1000, 256, 0, stream>>>(BU2, XMT, KM);
  for (int it = 1; it <= 10; it++)
    assign_k<<<250, 256, 0, stream>>>(XMT, KM + (it - 1) * ITST,
                                      (it < 10) ? KM + it * ITST : KM, IDX,
                                      (it == 10) ? 1 : 0,
                                      gkw1, gkb1, gkw2, gkb2, gkw3, gkb3,
                                      gbw1, gbb1, gbw2, gbb2, gbw3, gbb3,
                                      WI, BIAS);
  conv_k<<<2000, 256, 0, stream>>>(XPT, BWB, WI, BIAS, IDX, x, pa, outp);
}

// Round 11
// 309.590 us; speedup vs baseline: 1.1250x; 1.0926x over previous
//
#include <hip/hip_runtime.h>
#include <math.h>

typedef short v8s __attribute__((ext_vector_type(8)));
typedef float v4f __attribute__((ext_vector_type(4)));

#define NVOX 64000      // 40^3
#define NPAD 74088      // 42^3
#define P2   1764       // 42^2
#define GSTR 592704     // NPAD*8
#define NCPY 32         // banked global-accumulator copies
#define ITST (NCPY*260) // stride per kmeans iteration (8320 floats)

__device__ __forceinline__ unsigned short bf16rne(float f){
  unsigned int u = __float_as_uint(f);
  u += 0x7FFFu + ((u >> 16) & 1u);
  return (unsigned short)(u >> 16);
}

// ---------------- merged prep: projection (blocks 0..999, 4-way channel split)
// + base_w bf16 repack (1000..1431) + xpt halo zeroing (1432..1471)
// + KM accumulator zeroing (1472..1553) (must precede boxdt's atomic flush).
__global__ __launch_bounds__(256) void prep_k(const float* __restrict__ x,
                                              const float* __restrict__ pw,
                                              float* __restrict__ xp,
                                              short* __restrict__ xpt,
                                              const float* __restrict__ bw,
                                              short* __restrict__ bwb,
                                              float* __restrict__ km){
  int tid = threadIdx.x;
  int bid = blockIdx.x;
  if (bid < 1000){
    int m = (bid >> 2) * 256 + tid;
    int quarter = bid & 3;
    float xv[64];
#pragma unroll
    for (int i = 0; i < 64; i++) xv[i] = x[(size_t)i * NVOX + m];
    int d = m / 1600; int r = m - d * 1600; int h = r / 40; int w = r - h * 40;
    int p = ((d + 1) * 42 + (h + 1)) * 42 + (w + 1);
    const float4* pw4 = (const float4*)pw;
    for (int g8 = quarter * 2; g8 < quarter * 2 + 2; g8++){
      v8s pk;
#pragma unroll
      for (int j = 0; j < 8; j++){
        int co = g8 * 8 + j;
        float acc = 0.f;
#pragma unroll
        for (int q = 0; q < 16; q++){
          float4 pv = pw4[co * 16 + q];   // wave-uniform -> scalar K$ loads
          acc = fmaf(pv.x, xv[4*q+0], acc);
          acc = fmaf(pv.y, xv[4*q+1], acc);
          acc = fmaf(pv.z, xv[4*q+2], acc);
          acc = fmaf(pv.w, xv[4*q+3], acc);
        }
        xp[(size_t)co * NVOX + m] = acc;
        pk[j] = (short)bf16rne(acc);
      }
      *(v8s*)(xpt + (size_t)g8 * GSTR + (size_t)p * 8) = pk;
    }
  } else if (bid < 1432){
    int e = (bid - 1000) * 256 + tid;               // 0 .. 110591
    int t5 = e >> 12; int rem = e & 4095;
    int o = rem >> 6; int c = rem & 63;
    bwb[e] = (short)bf16rne(bw[(o * 64 + c) * 27 + t5]);
  } else if (bid < 1472){
    v8s z = (v8s){0,0,0,0,0,0,0,0};
    for (int p = (bid - 1432) * 256 + tid; p < NPAD; p += 40 * 256){
      int d = p / P2; int rem = p - d * P2; int h = rem / 42; int w = rem - h * 42;
      if (d == 0 || d == 41 || h == 0 || h == 41 || w == 0 || w == 41){
#pragma unroll
        for (int g = 0; g < 8; g++)
          *(v8s*)(xpt + (size_t)g * GSTR + (size_t)p * 8) = z;
      }
    }
  } else {
    for (int j = (bid - 1472) * 256 + tid; j < 10 * ITST; j += 82 * 256)
      km[j] = 0.f;
  }
}

// ---------------- fused w+h box passes per (c,d) slice (zero pad) — R6-proven
__global__ __launch_bounds__(256) void boxwh_k(const float* __restrict__ in,
                                               float* __restrict__ out){
  __shared__ float s0[1600], s1[1600];
  size_t base = (size_t)blockIdx.x * 1600;
  int t = threadIdx.x;
  for (int e = t; e < 1600; e += 256) s0[e] = in[base + e];
  __syncthreads();
  for (int e = t; e < 1600; e += 256){
    int w = e % 40;
    float s = s0[e];
    if (w > 0)  s += s0[e - 1];
    if (w < 39) s += s0[e + 1];
    s1[e] = s;
  }
  __syncthreads();
  for (int e = t; e < 1600; e += 256){
    int h = e / 40;
    float s = s1[e];
    if (h > 0)  s += s1[e - 40];
    if (h < 39) s += s1[e + 40];
    out[base + e] = s;
  }
}

// ---------------- fused boxd + transpose + kmeans-iter0 (R10-proven).
__global__ __launch_bounds__(256) void boxdt_k(const float* __restrict__ in,
                                               float* __restrict__ out,
                                               float* __restrict__ acc1){
  __shared__ float tile[64][65];
  __shared__ float s_cent[256];
  __shared__ float s_cc[4];
  __shared__ float s_red[260];
  __shared__ int   s_kb[64];
  int t = threadIdx.x;
  int nb = blockIdx.x * 64;
  int l = t & 63, g = t >> 6;
  {
    int k = t >> 6, c = t & 63;   // cent0[k][c] = (BU2[c][k] + BU2[c][k+1600])/27 (d=0)
    s_cent[t] = (in[(size_t)c * NVOX + k] + in[(size_t)c * NVOX + k + 1600]) * (1.f / 27.f);
  }
  for (int j = t; j < 260; j += 256) s_red[j] = 0.f;
  int n = nb + l;
  int d = n / 1600;
  for (int cc = g; cc < 64; cc += 4){
    const float* b = in + (size_t)cc * NVOX + n;
    float s = b[0];
    if (d > 0)  s += b[-1600];
    if (d < 39) s += b[1600];
    tile[cc][l] = s * (1.f / 27.f);
  }
  __syncthreads();
  if (t < 4){
    float s = 0.f;
    for (int c = 0; c < 64; c++){ float v = s_cent[t * 64 + c]; s = fmaf(v, v, s); }
    s_cc[t] = s;
  }
  __syncthreads();
  if (t < 64){
    float d0 = 0.f, d1 = 0.f, d2 = 0.f, d3 = 0.f;
    for (int c = 0; c < 64; c++){
      float v = tile[c][t];
      d0 = fmaf(s_cent[c], v, d0);
      d1 = fmaf(s_cent[64 + c], v, d1);
      d2 = fmaf(s_cent[128 + c], v, d2);
      d3 = fmaf(s_cent[192 + c], v, d3);
    }
    float sc0 = s_cc[0] - 2.f * d0;
    float sc1 = s_cc[1] - 2.f * d1;
    float sc2 = s_cc[2] - 2.f * d2;
    float sc3 = s_cc[3] - 2.f * d3;
    int kb = 0; float bs = sc0;
    if (sc1 < bs){ bs = sc1; kb = 1; }
    if (sc2 < bs){ bs = sc2; kb = 2; }
    if (sc3 < bs){ bs = sc3; kb = 3; }
    s_kb[t] = kb;
  }
  __syncthreads();
  {
    int lane = t & 63, wv = t >> 6;
    float a0 = 0.f, a1 = 0.f, a2 = 0.f, a3 = 0.f;
#pragma unroll
    for (int j = 0; j < 16; j++){
      int p = wv * 16 + j;
      float v = tile[lane][p];
      int kj = s_kb[p];
      a0 += (kj == 0) ? v : 0.f;
      a1 += (kj == 1) ? v : 0.f;
      a2 += (kj == 2) ? v : 0.f;
      a3 += (kj == 3) ? v : 0.f;
    }
    atomicAdd(&s_red[lane], a0);
    atomicAdd(&s_red[64 + lane], a1);
    atomicAdd(&s_red[128 + lane], a2);
    atomicAdd(&s_red[192 + lane], a3);
  }
  if (t < 4){
    float c = 0.f;
    for (int p = 0; p < 64; p++) c += (s_kb[p] == t) ? 1.f : 0.f;
    s_red[256 + t] = c;     // single writer per slot
  }
  __syncthreads();
  float* kslot = acc1 + (blockIdx.x & (NCPY - 1)) * 260;
  for (int j = t; j < 260; j += 256) atomicAdd(&kslot[j], s_red[j]);
  for (int nn = g; nn < 64; nn += 4)
    out[(size_t)(nb + nn) * 64 + l] = tile[l][nn];
}

// ---------------- kmeans assign + reduce (mode 0) or idx write + MLPs (mode 1)
__global__ __launch_bounds__(256) void assign_k(const float* __restrict__ xmt,
                                                const float* __restrict__ kin,
                                                float* __restrict__ kout,
                                                int* __restrict__ idx, int mode,
                      const float* __restrict__ w1, const float* __restrict__ b1,
                      const float* __restrict__ w2, const float* __restrict__ b2,
                      const float* __restrict__ w3, const float* __restrict__ b3,
                      const float* __restrict__ u1, const float* __restrict__ c1,
                      const float* __restrict__ u2, const float* __restrict__ c2,
                      const float* __restrict__ u3, const float* __restrict__ c3,
                      float* __restrict__ wi, float* __restrict__ bias){
  __shared__ float s_cent[256];
  __shared__ float s_cc[4];
  __shared__ float s_red[260];
  __shared__ float s_x[256 * 65];
  __shared__ int   s_kb[256];
  __shared__ float s_h1[128], s_h2[128], s_g1[64], s_g2[64];
  int t = threadIdx.x, lane = t & 63, wv = t >> 6;
  int n = blockIdx.x * 256 + t;
  {
    float sum = 0.f, cnt = 0.f;
#pragma unroll
    for (int s = 0; s < NCPY; s++){
      sum += kin[s * 260 + t];
      cnt += kin[s * 260 + 256 + (t >> 6)];
    }
    s_cent[t] = sum / fmaxf(cnt, 1.f);
  }
  for (int j = t; j < 260; j += 256) s_red[j] = 0.f;
  __syncthreads();
  if (t < 4){
    const float4* cc4 = (const float4*)(s_cent + t * 64);
    float s = 0.f;
#pragma unroll
    for (int q = 0; q < 16; q++){
      float4 v = cc4[q];
      s = fmaf(v.x, v.x, s); s = fmaf(v.y, v.y, s);
      s = fmaf(v.z, v.z, s); s = fmaf(v.w, v.w, s);
    }
    s_cc[t] = s;
  }
  __syncthreads();
  const float4* xt = (const float4*)(xmt + (size_t)n * 64);
  float4 xq[16];
#pragma unroll
  for (int q = 0; q < 16; q++) xq[q] = xt[q];
  float d0 = 0.f, d1 = 0.f, d2 = 0.f, d3 = 0.f;
  const float4* c4 = (const float4*)s_cent;
#pragma unroll
  for (int q = 0; q < 16; q++){
    float4 p0 = c4[q], p1 = c4[16 + q], p2 = c4[32 + q], p3 = c4[48 + q];
    d0 = fmaf(p0.x, xq[q].x, d0); d0 = fmaf(p0.y, xq[q].y, d0);
    d0 = fmaf(p0.z, xq[q].z, d0); d0 = fmaf(p0.w, xq[q].w, d0);
    d1 = fmaf(p1.x, xq[q].x, d1); d1 = fmaf(p1.y, xq[q].y, d1);
    d1 = fmaf(p1.z, xq[q].z, d1); d1 = fmaf(p1.w, xq[q].w, d1);
    d2 = fmaf(p2.x, xq[q].x, d2); d2 = fmaf(p2.y, xq[q].y, d2);
    d2 = fmaf(p2.z, xq[q].z, d2); d2 = fmaf(p2.w, xq[q].w, d2);
    d3 = fmaf(p3.x, xq[q].x, d3); d3 = fmaf(p3.y, xq[q].y, d3);
    d3 = fmaf(p3.z, xq[q].z, d3); d3 = fmaf(p3.w, xq[q].w, d3);
  }
  float sc0 = s_cc[0] - 2.f * d0;
  float sc1 = s_cc[1] - 2.f * d1;
  float sc2 = s_cc[2] - 2.f * d2;
  float sc3 = s_cc[3] - 2.f * d3;
  int kb = 0; float bs = sc0;
  if (sc1 < bs){ bs = sc1; kb = 1; }
  if (sc2 < bs){ bs = sc2; kb = 2; }
  if (sc3 < bs){ bs = sc3; kb = 3; }
  if (mode){
    idx[n] = kb;
    if (blockIdx.x == 0){
      __syncthreads();
      if (t < 128){
        float z = b1[t];
        for (int i = 0; i < 256; i++) z = fmaf(s_cent[i], w1[i * 128 + t], z);
        s_h1[t] = fmaxf(z, 0.f);
      }
      if (t < 64){
        float z = c1[t];
        for (int i = 0; i < 256; i++) z = fmaf(s_cent[i], u1[i * 64 + t], z);
        s_g1[t] = fmaxf(z, 0.f);
      }
      __syncthreads();
      if (t < 128){
        float z = b2[t];
        for (int i = 0; i < 128; i++) z = fmaf(s_h1[i], w2[i * 128 + t], z);
        s_h2[t] = fmaxf(z, 0.f);
      }
      if (t < 64){
        float z = c2[t];
        for (int i = 0; i < 64; i++) z = fmaf(s_g1[i], u2[i * 64 + t], z);
        s_g2[t] = fmaxf(z, 0.f);
      }
      __syncthreads();
      if (t < 108){
        float z = b3[t];
        for (int i = 0; i < 128; i++) z = fmaf(s_h2[i], w3[i * 108 + t], z);
        wi[t] = 1.f / (1.f + expf(-z));
      }
      {
        float z = c3[t];
        for (int i = 0; i < 64; i++) z = fmaf(s_g2[i], u3[i * 256 + t], z);
        bias[t] = z;
      }
    }
    return;
  }
  s_kb[t] = kb;
#pragma unroll
  for (int q = 0; q < 16; q++){
    s_x[t * 65 + 4*q + 0] = xq[q].x;
    s_x[t * 65 + 4*q + 1] = xq[q].y;
    s_x[t * 65 + 4*q + 2] = xq[q].z;
    s_x[t * 65 + 4*q + 3] = xq[q].w;
  }
  __syncthreads();
  float a0 = 0.f, a1 = 0.f, a2 = 0.f, a3 = 0.f;
  int rowbase = wv * 64;
#pragma unroll 16
  for (int j = 0; j < 64; j++){
    float v = s_x[(rowbase + j) * 65 + lane];
    int kj = s_kb[rowbase + j];
    a0 += (kj == 0) ? v : 0.f;
    a1 += (kj == 1) ? v : 0.f;
    a2 += (kj == 2) ? v : 0.f;
    a3 += (kj == 3) ? v : 0.f;
  }
  atomicAdd(&s_red[lane], a0);
  atomicAdd(&s_red[64 + lane], a1);
  atomicAdd(&s_red[128 + lane], a2);
  atomicAdd(&s_red[192 + lane], a3);
#pragma unroll
  for (int kk = 0; kk < 4; kk++){
    unsigned long long m = __ballot(kb == kk);
    if (lane == 0) atomicAdd(&s_red[256 + kk], (float)__popcll(m));
  }
  __syncthreads();
  float* kslot = kout + (blockIdx.x & (NCPY - 1)) * 260;
  for (int j = t; j < 260; j += 256) atomicAdd(&kslot[j], s_red[j]);
}

// ---------------- main dynamic conv (R6-verbatim, proven 49us).
// 1000 blocks x 64-voxel tiles is the halo-reuse sweet spot: o-split (R9) and
// n-split (R10) both blew FETCH 28->43MB (per-XCD L2, no cross-XCD sharing).
__global__ __launch_bounds__(256) void conv_k(const short* __restrict__ xpt,
                                              const short* __restrict__ bwb,
                                              const float* __restrict__ wi,
                                              const float* __restrict__ bias,
                                              const int* __restrict__ idx,
                                              const float* __restrict__ x,
                                              const float* __restrict__ pa,
                                              float* __restrict__ out){
  static const int POFF[27] = {
    -P2-42-1, -P2-42, -P2-42+1, -P2-1, -P2, -P2+1, -P2+42-1, -P2+42, -P2+42+1,
    -42-1, -42, -42+1, -1, 0, 1, 42-1, 42, 42+1,
    P2-42-1, P2-42, P2-42+1, P2-1, P2, P2+1, P2+42-1, P2+42, P2+42+1 };
  __shared__ float s_wi[108];
  __shared__ float s_bias[256];
  __shared__ float s_acc[64 * 68];
  int tid = threadIdx.x;
  for (int j = tid; j < 108; j += 256) s_wi[j] = wi[j];
  s_bias[tid] = bias[tid];
  __syncthreads();
  int wv = tid >> 6, lane = tid & 63;
  int kc = wv & 1, mh = wv >> 1;
  int col = lane & 15, kg = lane >> 4;
  int vb = blockIdx.x * 64;
  int p4[4], ki4[4];
#pragma unroll
  for (int nt = 0; nt < 4; nt++){
    int v = vb + nt * 16 + col;
    ki4[nt] = idx[v];
    int d = v / 1600; int r = v - d * 1600; int h = r / 40; int w = r - h * 40;
    p4[nt] = ((d + 1) * 42 + (h + 1)) * 42 + (w + 1);
  }
  const short* bg = xpt + (size_t)(kc * 4 + kg) * GSTR;
  const short* bp0 = bg + (size_t)p4[0] * 8;
  const short* bp1 = bg + (size_t)p4[1] * 8;
  const short* bp2 = bg + (size_t)p4[2] * 8;
  const short* bp3 = bg + (size_t)p4[3] * 8;
  int ao0 = (mh * 32 + col) * 64 + kc * 32 + kg * 8;
  int ao1 = ao0 + 16 * 64;
  v4f acc[2][4];
#pragma unroll
  for (int m2 = 0; m2 < 2; m2++)
#pragma unroll
    for (int nt = 0; nt < 4; nt++) acc[m2][nt] = (v4f){0.f, 0.f, 0.f, 0.f};
  v4f zero = {0.f, 0.f, 0.f, 0.f};
#pragma unroll 9
  for (int t = 0; t < 27; t++){
    int po8 = POFF[t] * 8;
    v8s a0 = *(const v8s*)(bwb + t * 4096 + ao0);
    v8s a1 = *(const v8s*)(bwb + t * 4096 + ao1);
    v8s b0 = *(const v8s*)(bp0 + po8);
    v8s b1 = *(const v8s*)(bp1 + po8);
    v8s b2 = *(const v8s*)(bp2 + po8);
    v8s b3 = *(const v8s*)(bp3 + po8);
    float wk0 = s_wi[ki4[0] * 27 + t];
    float wk1 = s_wi[ki4[1] * 27 + t];
    float wk2 = s_wi[ki4[2] * 27 + t];
    float wk3 = s_wi[ki4[3] * 27 + t];
    v4f tp;
    tp = __builtin_amdgcn_mfma_f32_16x16x32_bf16(a0, b0, zero, 0, 0, 0); acc[0][0] += tp * wk0;
    tp = __builtin_amdgcn_mfma_f32_16x16x32_bf16(a1, b0, zero, 0, 0, 0); acc[1][0] += tp * wk0;
    tp = __builtin_amdgcn_mfma_f32_16x16x32_bf16(a0, b1, zero, 0, 0, 0); acc[0][1] += tp * wk1;
    tp = __builtin_amdgcn_mfma_f32_16x16x32_bf16(a1, b1, zero, 0, 0, 0); acc[1][1] += tp * wk1;
    tp = __builtin_amdgcn_mfma_f32_16x16x32_bf16(a0, b2, zero, 0, 0, 0); acc[0][2] += tp * wk2;
    tp = __builtin_amdgcn_mfma_f32_16x16x32_bf16(a1, b2, zero, 0, 0, 0); acc[1][2] += tp * wk2;
    tp = __builtin_amdgcn_mfma_f32_16x16x32_bf16(a0, b3, zero, 0, 0, 0); acc[0][3] += tp * wk3;
    tp = __builtin_amdgcn_mfma_f32_16x16x32_bf16(a1, b3, zero, 0, 0, 0); acc[1][3] += tp * wk3;
  }
  __syncthreads();
  if (kc == 1){
#pragma unroll
    for (int m2 = 0; m2 < 2; m2++)
#pragma unroll
      for (int nt = 0; nt < 4; nt++)
        *(v4f*)(&s_acc[(nt * 16 + col) * 68 + mh * 32 + m2 * 16 + kg * 4]) = acc[m2][nt];
  }
  __syncthreads();
  if (kc == 0){
    float pav = pa[0];
#pragma unroll
    for (int m2 = 0; m2 < 2; m2++){
#pragma unroll
      for (int nt = 0; nt < 4; nt++){
        v4f other = *(const v4f*)(&s_acc[(nt * 16 + col) * 68 + mh * 32 + m2 * 16 + kg * 4]);
        v4f sum = acc[m2][nt] + other;
        int n = vb + nt * 16 + col;
#pragma unroll
        for (int r = 0; r < 4; r++){
          int o = mh * 32 + m2 * 16 + kg * 4 + r;
          float val = sum[r] + s_bias[ki4[nt] * 64 + o];
          val = (val >= 0.f) ? val : pav * val;
          size_t off = (size_t)o * NVOX + n;
          out[off] = val + x[off];
        }
      }
    }
  }
}

extern "C" void kernel_launch(void* const* d_in, const int* in_sizes, int n_in,
                              void* d_out, int out_size, void* d_ws, size_t ws_size,
                              hipStream_t stream){
  const float* x    = (const float*)d_in[0];
  const float* pw   = (const float*)d_in[1];
  const float* bw   = (const float*)d_in[2];
  const float* gkw1 = (const float*)d_in[3];
  const float* gkb1 = (const float*)d_in[4];
  const float* gkw2 = (const float*)d_in[5];
  const float* gkb2 = (const float*)d_in[6];
  const float* gkw3 = (const float*)d_in[7];
  const float* gkb3 = (const float*)d_in[8];
  const float* gbw1 = (const float*)d_in[9];
  const float* gbb1 = (const float*)d_in[10];
  const float* gbw2 = (const float*)d_in[11];
  const float* gbb2 = (const float*)d_in[12];
  const float* gbw3 = (const float*)d_in[13];
  const float* gbb3 = (const float*)d_in[14];
  const float* pa   = (const float*)d_in[15];
  float* outp = (float*)d_out;

  float* ws   = (float*)d_ws;
  float* XP   = ws;                                  // 4,096,000 f ; reused as XMT
  float* BU2  = ws + 4096000;                        // 4,096,000 f (wh-filtered)
  short* XPT  = (short*)(ws + 12288000);             // 4,741,632 s
  short* BWB  = XPT + (size_t)NPAD * 64;             // 110,592 s
  float* KM   = (float*)(BWB + 110592);              // 10*8320 f  (ACC[1..10])
  float* WI   = KM + 10 * ITST;                      // 108 f
  float* BIAS = WI + 108;                            // 256 f
  int*   IDX  = (int*)(BIAS + 256);                  // 64,000 i
  float* XMT  = XP;                                  // xm transposed [n][c]

  prep_k<<<1554, 256, 0, stream>>>(x, pw, XP, XPT, bw, BWB, KM);
  boxwh_k<<<2560, 256, 0, stream>>>(XP, BU2);
  boxdt_k<<<1000, 256, 0, stream>>>(BU2, XMT, KM);
  for (int it = 1; it <= 10; it++)
    assign_k<<<250, 256, 0, stream>>>(XMT, KM + (it - 1) * ITST,
                                      (it < 10) ? KM + it * ITST : KM, IDX,
                                      (it == 10) ? 1 : 0,
                                      gkw1, gkb1, gkw2, gkb2, gkw3, gkb3,
                                      gbw1, gbb1, gbw2, gbb2, gbw3, gbb3,
                                      WI, BIAS);
  conv_k<<<1000, 256, 0, stream>>>(XPT, BWB, WI, BIAS, IDX, x, pa, outp);
}

// Round 12
// 307.981 us; speedup vs baseline: 1.1309x; 1.0052x over previous
//
#include <hip/hip_runtime.h>
#include <math.h>

typedef short v8s __attribute__((ext_vector_type(8)));
typedef float v4f __attribute__((ext_vector_type(4)));

#define NVOX 64000      // 40^3
#define NPAD 74088      // 42^3
#define P2   1764       // 42^2
#define GSTR 592704     // NPAD*8
#define NCPY 32         // banked global-accumulator copies
#define ITST (NCPY*260) // stride per kmeans iteration (8320 floats)

__device__ __forceinline__ unsigned short bf16rne(float f){
  unsigned int u = __float_as_uint(f);
  u += 0x7FFFu + ((u >> 16) & 1u);
  return (unsigned short)(u >> 16);
}

// ---------------- merged prep: projection (blocks 0..999, 4-way channel split)
// + base_w bf16 repack (1000..1431) + xpt halo zeroing (1432..1471)
// + KM accumulator zeroing (1472..1553) (must precede boxdt's atomic flush).
__global__ __launch_bounds__(256) void prep_k(const float* __restrict__ x,
                                              const float* __restrict__ pw,
                                              float* __restrict__ xp,
                                              short* __restrict__ xpt,
                                              const float* __restrict__ bw,
                                              short* __restrict__ bwb,
                                              float* __restrict__ km){
  int tid = threadIdx.x;
  int bid = blockIdx.x;
  if (bid < 1000){
    int m = (bid >> 2) * 256 + tid;
    int quarter = bid & 3;
    float xv[64];
#pragma unroll
    for (int i = 0; i < 64; i++) xv[i] = x[(size_t)i * NVOX + m];
    int d = m / 1600; int r = m - d * 1600; int h = r / 40; int w = r - h * 40;
    int p = ((d + 1) * 42 + (h + 1)) * 42 + (w + 1);
    const float4* pw4 = (const float4*)pw;
    for (int g8 = quarter * 2; g8 < quarter * 2 + 2; g8++){
      v8s pk;
#pragma unroll
      for (int j = 0; j < 8; j++){
        int co = g8 * 8 + j;
        float acc = 0.f;
#pragma unroll
        for (int q = 0; q < 16; q++){
          float4 pv = pw4[co * 16 + q];   // wave-uniform -> scalar K$ loads
          acc = fmaf(pv.x, xv[4*q+0], acc);
          acc = fmaf(pv.y, xv[4*q+1], acc);
          acc = fmaf(pv.z, xv[4*q+2], acc);
          acc = fmaf(pv.w, xv[4*q+3], acc);
        }
        xp[(size_t)co * NVOX + m] = acc;
        pk[j] = (short)bf16rne(acc);
      }
      *(v8s*)(xpt + (size_t)g8 * GSTR + (size_t)p * 8) = pk;
    }
  } else if (bid < 1432){
    int e = (bid - 1000) * 256 + tid;               // 0 .. 110591
    int t5 = e >> 12; int rem = e & 4095;
    int o = rem >> 6; int c = rem & 63;
    bwb[e] = (short)bf16rne(bw[(o * 64 + c) * 27 + t5]);
  } else if (bid < 1472){
    v8s z = (v8s){0,0,0,0,0,0,0,0};
    for (int p = (bid - 1432) * 256 + tid; p < NPAD; p += 40 * 256){
      int d = p / P2; int rem = p - d * P2; int h = rem / 42; int w = rem - h * 42;
      if (d == 0 || d == 41 || h == 0 || h == 41 || w == 0 || w == 41){
#pragma unroll
        for (int g = 0; g < 8; g++)
          *(v8s*)(xpt + (size_t)g * GSTR + (size_t)p * 8) = z;
      }
    }
  } else {
    for (int j = (bid - 1472) * 256 + tid; j < 10 * ITST; j += 82 * 256)
      km[j] = 0.f;
  }
}

// ---------------- fused w+h box passes per (c,d) slice (zero pad) — R6-proven
__global__ __launch_bounds__(256) void boxwh_k(const float* __restrict__ in,
                                               float* __restrict__ out){
  __shared__ float s0[1600], s1[1600];
  size_t base = (size_t)blockIdx.x * 1600;
  int t = threadIdx.x;
  for (int e = t; e < 1600; e += 256) s0[e] = in[base + e];
  __syncthreads();
  for (int e = t; e < 1600; e += 256){
    int w = e % 40;
    float s = s0[e];
    if (w > 0)  s += s0[e - 1];
    if (w < 39) s += s0[e + 1];
    s1[e] = s;
  }
  __syncthreads();
  for (int e = t; e < 1600; e += 256){
    int h = e / 40;
    float s = s1[e];
    if (h > 0)  s += s1[e - 40];
    if (h < 39) s += s1[e + 40];
    out[base + e] = s;
  }
}

// ---------------- fused boxd + transpose + kmeans-iter0 (R10-proven).
__global__ __launch_bounds__(256) void boxdt_k(const float* __restrict__ in,
                                               float* __restrict__ out,
                                               float* __restrict__ acc1){
  __shared__ float tile[64][65];
  __shared__ float s_cent[256];
  __shared__ float s_cc[4];
  __shared__ float s_red[260];
  __shared__ int   s_kb[64];
  int t = threadIdx.x;
  int nb = blockIdx.x * 64;
  int l = t & 63, g = t >> 6;
  {
    int k = t >> 6, c = t & 63;   // cent0[k][c] = (BU2[c][k] + BU2[c][k+1600])/27 (d=0)
    s_cent[t] = (in[(size_t)c * NVOX + k] + in[(size_t)c * NVOX + k + 1600]) * (1.f / 27.f);
  }
  for (int j = t; j < 260; j += 256) s_red[j] = 0.f;
  int n = nb + l;
  int d = n / 1600;
  for (int cc = g; cc < 64; cc += 4){
    const float* b = in + (size_t)cc * NVOX + n;
    float s = b[0];
    if (d > 0)  s += b[-1600];
    if (d < 39) s += b[1600];
    tile[cc][l] = s * (1.f / 27.f);
  }
  __syncthreads();
  if (t < 4){
    float s = 0.f;
    for (int c = 0; c < 64; c++){ float v = s_cent[t * 64 + c]; s = fmaf(v, v, s); }
    s_cc[t] = s;
  }
  __syncthreads();
  if (t < 64){
    float d0 = 0.f, d1 = 0.f, d2 = 0.f, d3 = 0.f;
    for (int c = 0; c < 64; c++){
      float v = tile[c][t];
      d0 = fmaf(s_cent[c], v, d0);
      d1 = fmaf(s_cent[64 + c], v, d1);
      d2 = fmaf(s_cent[128 + c], v, d2);
      d3 = fmaf(s_cent[192 + c], v, d3);
    }
    float sc0 = s_cc[0] - 2.f * d0;
    float sc1 = s_cc[1] - 2.f * d1;
    float sc2 = s_cc[2] - 2.f * d2;
    float sc3 = s_cc[3] - 2.f * d3;
    int kb = 0; float bs = sc0;
    if (sc1 < bs){ bs = sc1; kb = 1; }
    if (sc2 < bs){ bs = sc2; kb = 2; }
    if (sc3 < bs){ bs = sc3; kb = 3; }
    s_kb[t] = kb;
  }
  __syncthreads();
  {
    int lane = t & 63, wv = t >> 6;
    float a0 = 0.f, a1 = 0.f, a2 = 0.f, a3 = 0.f;
#pragma unroll
    for (int j = 0; j < 16; j++){
      int p = wv * 16 + j;
      float v = tile[lane][p];
      int kj = s_kb[p];
      a0 += (kj == 0) ? v : 0.f;
      a1 += (kj == 1) ? v : 0.f;
      a2 += (kj == 2) ? v : 0.f;
      a3 += (kj == 3) ? v : 0.f;
    }
    atomicAdd(&s_red[lane], a0);
    atomicAdd(&s_red[64 + lane], a1);
    atomicAdd(&s_red[128 + lane], a2);
    atomicAdd(&s_red[192 + lane], a3);
  }
  if (t < 4){
    float c = 0.f;
    for (int p = 0; p < 64; p++) c += (s_kb[p] == t) ? 1.f : 0.f;
    s_red[256 + t] = c;     // single writer per slot
  }
  __syncthreads();
  float* kslot = acc1 + (blockIdx.x & (NCPY - 1)) * 260;
  for (int j = t; j < 260; j += 256) atomicAdd(&kslot[j], s_red[j]);
  for (int nn = g; nn < 64; nn += 4)
    out[(size_t)(nb + nn) * 64 + l] = tile[l][nn];
}

// ---------------- kmeans assign + reduce (always the old mode 0; the final
// assignment + MLPs moved into conv_k).
__global__ __launch_bounds__(256) void assign_k(const float* __restrict__ xmt,
                                                const float* __restrict__ kin,
                                                float* __restrict__ kout){
  __shared__ float s_cent[256];
  __shared__ float s_cc[4];
  __shared__ float s_red[260];
  __shared__ float s_x[256 * 65];
  __shared__ int   s_kb[256];
  int t = threadIdx.x, lane = t & 63, wv = t >> 6;
  int n = blockIdx.x * 256 + t;
  {
    float sum = 0.f, cnt = 0.f;
#pragma unroll
    for (int s = 0; s < NCPY; s++){
      sum += kin[s * 260 + t];
      cnt += kin[s * 260 + 256 + (t >> 6)];
    }
    s_cent[t] = sum / fmaxf(cnt, 1.f);
  }
  for (int j = t; j < 260; j += 256) s_red[j] = 0.f;
  __syncthreads();
  if (t < 4){
    const float4* cc4 = (const float4*)(s_cent + t * 64);
    float s = 0.f;
#pragma unroll
    for (int q = 0; q < 16; q++){
      float4 v = cc4[q];
      s = fmaf(v.x, v.x, s); s = fmaf(v.y, v.y, s);
      s = fmaf(v.z, v.z, s); s = fmaf(v.w, v.w, s);
    }
    s_cc[t] = s;
  }
  __syncthreads();
  const float4* xt = (const float4*)(xmt + (size_t)n * 64);
  float4 xq[16];
#pragma unroll
  for (int q = 0; q < 16; q++) xq[q] = xt[q];
  float d0 = 0.f, d1 = 0.f, d2 = 0.f, d3 = 0.f;
  const float4* c4 = (const float4*)s_cent;
#pragma unroll
  for (int q = 0; q < 16; q++){
    float4 p0 = c4[q], p1 = c4[16 + q], p2 = c4[32 + q], p3 = c4[48 + q];
    d0 = fmaf(p0.x, xq[q].x, d0); d0 = fmaf(p0.y, xq[q].y, d0);
    d0 = fmaf(p0.z, xq[q].z, d0); d0 = fmaf(p0.w, xq[q].w, d0);
    d1 = fmaf(p1.x, xq[q].x, d1); d1 = fmaf(p1.y, xq[q].y, d1);
    d1 = fmaf(p1.z, xq[q].z, d1); d1 = fmaf(p1.w, xq[q].w, d1);
    d2 = fmaf(p2.x, xq[q].x, d2); d2 = fmaf(p2.y, xq[q].y, d2);
    d2 = fmaf(p2.z, xq[q].z, d2); d2 = fmaf(p2.w, xq[q].w, d2);
    d3 = fmaf(p3.x, xq[q].x, d3); d3 = fmaf(p3.y, xq[q].y, d3);
    d3 = fmaf(p3.z, xq[q].z, d3); d3 = fmaf(p3.w, xq[q].w, d3);
  }
  float sc0 = s_cc[0] - 2.f * d0;
  float sc1 = s_cc[1] - 2.f * d1;
  float sc2 = s_cc[2] - 2.f * d2;
  float sc3 = s_cc[3] - 2.f * d3;
  int kb = 0; float bs = sc0;
  if (sc1 < bs){ bs = sc1; kb = 1; }
  if (sc2 < bs){ bs = sc2; kb = 2; }
  if (sc3 < bs){ bs = sc3; kb = 3; }
  s_kb[t] = kb;
#pragma unroll
  for (int q = 0; q < 16; q++){
    s_x[t * 65 + 4*q + 0] = xq[q].x;
    s_x[t * 65 + 4*q + 1] = xq[q].y;
    s_x[t * 65 + 4*q + 2] = xq[q].z;
    s_x[t * 65 + 4*q + 3] = xq[q].w;
  }
  __syncthreads();
  float a0 = 0.f, a1 = 0.f, a2 = 0.f, a3 = 0.f;
  int rowbase = wv * 64;
#pragma unroll 16
  for (int j = 0; j < 64; j++){
    float v = s_x[(rowbase + j) * 65 + lane];
    int kj = s_kb[rowbase + j];
    a0 += (kj == 0) ? v : 0.f;
    a1 += (kj == 1) ? v : 0.f;
    a2 += (kj == 2) ? v : 0.f;
    a3 += (kj == 3) ? v : 0.f;
  }
  atomicAdd(&s_red[lane], a0);
  atomicAdd(&s_red[64 + lane], a1);
  atomicAdd(&s_red[128 + lane], a2);
  atomicAdd(&s_red[192 + lane], a3);
#pragma unroll
  for (int kk = 0; kk < 4; kk++){
    unsigned long long m = __ballot(kb == kk);
    if (lane == 0) atomicAdd(&s_red[256 + kk], (float)__popcll(m));
  }
  __syncthreads();
  float* kslot = kout + (blockIdx.x & (NCPY - 1)) * 260;
  for (int j = t; j < 260; j += 256) atomicAdd(&kslot[j], s_red[j]);
}

// ---------------- main dynamic conv + final kmeans assignment + gating MLPs.
// Prologue per block: cent10 from the banked acc10 (bit-identical summation),
// own 64-voxel assignment (verbatim distance code), both MLPs redundantly
// (L2-hot weights) filling s_wi/s_bias. Removes the mode-1 assign node.
// Conv proper is R6-verbatim (1000 blocks x 64-voxel halo sweet spot).
__global__ __launch_bounds__(256) void conv_k(const short* __restrict__ xpt,
                                              const short* __restrict__ bwb,
                                              const float* __restrict__ km,
                                              const float* __restrict__ xmt,
                                              const float* __restrict__ x,
                                              const float* __restrict__ pa,
                                              float* __restrict__ out,
                      const float* __restrict__ w1, const float* __restrict__ b1,
                      const float* __restrict__ w2, const float* __restrict__ b2,
                      const float* __restrict__ w3, const float* __restrict__ b3,
                      const float* __restrict__ u1, const float* __restrict__ c1,
                      const float* __restrict__ u2, const float* __restrict__ c2,
                      const float* __restrict__ u3, const float* __restrict__ c3){
  static const int POFF[27] = {
    -P2-42-1, -P2-42, -P2-42+1, -P2-1, -P2, -P2+1, -P2+42-1, -P2+42, -P2+42+1,
    -42-1, -42, -42+1, -1, 0, 1, 42-1, 42, 42+1,
    P2-42-1, P2-42, P2-42+1, P2-1, P2, P2+1, P2+42-1, P2+42, P2+42+1 };
  __shared__ float s_wi[108];
  __shared__ float s_bias[256];
  __shared__ float s_acc[64 * 68];
  __shared__ float s_cent[256];
  __shared__ float s_cc[4];
  __shared__ int   s_kb[64];
  __shared__ float s_h1[128], s_h2[128], s_g1[64], s_g2[64];
  int tid = threadIdx.x;
  int vb = blockIdx.x * 64;
  // ---- cent10 (identical summation to assign_k's centroid load)
  {
    float sum = 0.f, cnt = 0.f;
#pragma unroll
    for (int s = 0; s < NCPY; s++){
      sum += km[s * 260 + tid];
      cnt += km[s * 260 + 256 + (tid >> 6)];
    }
    s_cent[tid] = sum / fmaxf(cnt, 1.f);
  }
  __syncthreads();
  if (tid < 4){
    const float4* cc4 = (const float4*)(s_cent + tid * 64);
    float s = 0.f;
#pragma unroll
    for (int q = 0; q < 16; q++){
      float4 v = cc4[q];
      s = fmaf(v.x, v.x, s); s = fmaf(v.y, v.y, s);
      s = fmaf(v.z, v.z, s); s = fmaf(v.w, v.w, s);
    }
    s_cc[tid] = s;
  }
  __syncthreads();
  // ---- final assignment for this block's 64 voxels (verbatim distance code)
  if (tid < 64){
    const float4* xt = (const float4*)(xmt + (size_t)(vb + tid) * 64);
    float4 xq[16];
#pragma unroll
    for (int q = 0; q < 16; q++) xq[q] = xt[q];
    float d0 = 0.f, d1 = 0.f, d2 = 0.f, d3 = 0.f;
    const float4* c4 = (const float4*)s_cent;
#pragma unroll
    for (int q = 0; q < 16; q++){
      float4 p0 = c4[q], p1 = c4[16 + q], p2 = c4[32 + q], p3 = c4[48 + q];
      d0 = fmaf(p0.x, xq[q].x, d0); d0 = fmaf(p0.y, xq[q].y, d0);
      d0 = fmaf(p0.z, xq[q].z, d0); d0 = fmaf(p0.w, xq[q].w, d0);
      d1 = fmaf(p1.x, xq[q].x, d1); d1 = fmaf(p1.y, xq[q].y, d1);
      d1 = fmaf(p1.z, xq[q].z, d1); d1 = fmaf(p1.w, xq[q].w, d1);
      d2 = fmaf(p2.x, xq[q].x, d2); d2 = fmaf(p2.y, xq[q].y, d2);
      d2 = fmaf(p2.z, xq[q].z, d2); d2 = fmaf(p2.w, xq[q].w, d2);
      d3 = fmaf(p3.x, xq[q].x, d3); d3 = fmaf(p3.y, xq[q].y, d3);
      d3 = fmaf(p3.z, xq[q].z, d3); d3 = fmaf(p3.w, xq[q].w, d3);
    }
    float sc0 = s_cc[0] - 2.f * d0;
    float sc1 = s_cc[1] - 2.f * d1;
    float sc2 = s_cc[2] - 2.f * d2;
    float sc3 = s_cc[3] - 2.f * d3;
    int kb = 0; float bs = sc0;
    if (sc1 < bs){ bs = sc1; kb = 1; }
    if (sc2 < bs){ bs = sc2; kb = 2; }
    if (sc3 < bs){ bs = sc3; kb = 3; }
    s_kb[tid] = kb;
  }
  // ---- gating MLPs (s_cent == mlp's s_feat; verbatim layer code)
  if (tid < 128){
    float z = b1[tid];
    for (int i = 0; i < 256; i++) z = fmaf(s_cent[i], w1[i * 128 + tid], z);
    s_h1[tid] = fmaxf(z, 0.f);
  }
  if (tid < 64){
    float z = c1[tid];
    for (int i = 0; i < 256; i++) z = fmaf(s_cent[i], u1[i * 64 + tid], z);
    s_g1[tid] = fmaxf(z, 0.f);
  }
  __syncthreads();
  if (tid < 128){
    float z = b2[tid];
    for (int i = 0; i < 128; i++) z = fmaf(s_h1[i], w2[i * 128 + tid], z);
    s_h2[tid] = fmaxf(z, 0.f);
  }
  if (tid < 64){
    float z = c2[tid];
    for (int i = 0; i < 64; i++) z = fmaf(s_g1[i], u2[i * 64 + tid], z);
    s_g2[tid] = fmaxf(z, 0.f);
  }
  __syncthreads();
  if (tid < 108){
    float z = b3[tid];
    for (int i = 0; i < 128; i++) z = fmaf(s_h2[i], w3[i * 108 + tid], z);
    s_wi[tid] = 1.f / (1.f + expf(-z));
  }
  {
    float z = c3[tid];
    for (int i = 0; i < 64; i++) z = fmaf(s_g2[i], u3[i * 256 + tid], z);
    s_bias[tid] = z;
  }
  __syncthreads();
  // ---- conv proper (R6-verbatim)
  int wv = tid >> 6, lane = tid & 63;
  int kc = wv & 1, mh = wv >> 1;
  int col = lane & 15, kg = lane >> 4;
  int p4[4], ki4[4];
#pragma unroll
  for (int nt = 0; nt < 4; nt++){
    int v = vb + nt * 16 + col;
    ki4[nt] = s_kb[nt * 16 + col];
    int d = v / 1600; int r = v - d * 1600; int h = r / 40; int w = r - h * 40;
    p4[nt] = ((d + 1) * 42 + (h + 1)) * 42 + (w + 1);
  }
  const short* bg = xpt + (size_t)(kc * 4 + kg) * GSTR;
  const short* bp0 = bg + (size_t)p4[0] * 8;
  const short* bp1 = bg + (size_t)p4[1] * 8;
  const short* bp2 = bg + (size_t)p4[2] * 8;
  const short* bp3 = bg + (size_t)p4[3] * 8;
  int ao0 = (mh * 32 + col) * 64 + kc * 32 + kg * 8;
  int ao1 = ao0 + 16 * 64;
  v4f acc[2][4];
#pragma unroll
  for (int m2 = 0; m2 < 2; m2++)
#pragma unroll
    for (int nt = 0; nt < 4; nt++) acc[m2][nt] = (v4f){0.f, 0.f, 0.f, 0.f};
  v4f zero = {0.f, 0.f, 0.f, 0.f};
#pragma unroll 9
  for (int t = 0; t < 27; t++){
    int po8 = POFF[t] * 8;
    v8s a0 = *(const v8s*)(bwb + t * 4096 + ao0);
    v8s a1 = *(const v8s*)(bwb + t * 4096 + ao1);
    v8s b0 = *(const v8s*)(bp0 + po8);
    v8s b1 = *(const v8s*)(bp1 + po8);
    v8s b2 = *(const v8s*)(bp2 + po8);
    v8s b3 = *(const v8s*)(bp3 + po8);
    float wk0 = s_wi[ki4[0] * 27 + t];
    float wk1 = s_wi[ki4[1] * 27 + t];
    float wk2 = s_wi[ki4[2] * 27 + t];
    float wk3 = s_wi[ki4[3] * 27 + t];
    v4f tp;
    tp = __builtin_amdgcn_mfma_f32_16x16x32_bf16(a0, b0, zero, 0, 0, 0); acc[0][0] += tp * wk0;
    tp = __builtin_amdgcn_mfma_f32_16x16x32_bf16(a1, b0, zero, 0, 0, 0); acc[1][0] += tp * wk0;
    tp = __builtin_amdgcn_mfma_f32_16x16x32_bf16(a0, b1, zero, 0, 0, 0); acc[0][1] += tp * wk1;
    tp = __builtin_amdgcn_mfma_f32_16x16x32_bf16(a1, b1, zero, 0, 0, 0); acc[1][1] += tp * wk1;
    tp = __builtin_amdgcn_mfma_f32_16x16x32_bf16(a0, b2, zero, 0, 0, 0); acc[0][2] += tp * wk2;
    tp = __builtin_amdgcn_mfma_f32_16x16x32_bf16(a1, b2, zero, 0, 0, 0); acc[1][2] += tp * wk2;
    tp = __builtin_amdgcn_mfma_f32_16x16x32_bf16(a0, b3, zero, 0, 0, 0); acc[0][3] += tp * wk3;
    tp = __builtin_amdgcn_mfma_f32_16x16x32_bf16(a1, b3, zero, 0, 0, 0); acc[1][3] += tp * wk3;
  }
  __syncthreads();
  if (kc == 1){
#pragma unroll
    for (int m2 = 0; m2 < 2; m2++)
#pragma unroll
      for (int nt = 0; nt < 4; nt++)
        *(v4f*)(&s_acc[(nt * 16 + col) * 68 + mh * 32 + m2 * 16 + kg * 4]) = acc[m2][nt];
  }
  __syncthreads();
  if (kc == 0){
    float pav = pa[0];
#pragma unroll
    for (int m2 = 0; m2 < 2; m2++){
#pragma unroll
      for (int nt = 0; nt < 4; nt++){
        v4f other = *(const v4f*)(&s_acc[(nt * 16 + col) * 68 + mh * 32 + m2 * 16 + kg * 4]);
        v4f sum = acc[m2][nt] + other;
        int n = vb + nt * 16 + col;
#pragma unroll
        for (int r = 0; r < 4; r++){
          int o = mh * 32 + m2 * 16 + kg * 4 + r;
          float val = sum[r] + s_bias[ki4[nt] * 64 + o];
          val = (val >= 0.f) ? val : pav * val;
          size_t off = (size_t)o * NVOX + n;
          out[off] = val + x[off];
        }
      }
    }
  }
}

extern "C" void kernel_launch(void* const* d_in, const int* in_sizes, int n_in,
                              void* d_out, int out_size, void* d_ws, size_t ws_size,
                              hipStream_t stream){
  const float* x    = (const float*)d_in[0];
  const float* pw   = (const float*)d_in[1];
  const float* bw   = (const float*)d_in[2];
  const float* gkw1 = (const float*)d_in[3];
  const float* gkb1 = (const float*)d_in[4];
  const float* gkw2 = (const float*)d_in[5];
  const float* gkb2 = (const float*)d_in[6];
  const float* gkw3 = (const float*)d_in[7];
  const float* gkb3 = (const float*)d_in[8];
  const float* gbw1 = (const float*)d_in[9];
  const float* gbb1 = (const float*)d_in[10];
  const float* gbw2 = (const float*)d_in[11];
  const float* gbb2 = (const float*)d_in[12];
  const float* gbw3 = (const float*)d_in[13];
  const float* gbb3 = (const float*)d_in[14];
  const float* pa   = (const float*)d_in[15];
  float* outp = (float*)d_out;

  float* ws   = (float*)d_ws;
  float* XP   = ws;                                  // 4,096,000 f ; reused as XMT
  float* BU2  = ws + 4096000;                        // 4,096,000 f (wh-filtered)
  short* XPT  = (short*)(ws + 12288000);             // 4,741,632 s
  short* BWB  = XPT + (size_t)NPAD * 64;             // 110,592 s
  float* KM   = (float*)(BWB + 110592);              // 10*8320 f  (ACC[1..10])
  float* XMT  = XP;                                  // xm transposed [n][c]

  prep_k<<<1554, 256, 0, stream>>>(x, pw, XP, XPT, bw, BWB, KM);
  boxwh_k<<<2560, 256, 0, stream>>>(XP, BU2);
  boxdt_k<<<1000, 256, 0, stream>>>(BU2, XMT, KM);
  for (int it = 1; it <= 9; it++)
    assign_k<<<250, 256, 0, stream>>>(XMT, KM + (it - 1) * ITST, KM + it * ITST);
  conv_k<<<1000, 256, 0, stream>>>(XPT, BWB, KM + 9 * ITST, XMT, x, pa, outp,
                                   gkw1, gkb1, gkw2, gkb2, gkw3, gkb3,
                                   gbw1, gbb1, gbw2, gbb2, gbw3, gbb3);
}

// Round 13
// 304.617 us; speedup vs baseline: 1.1434x; 1.0110x over previous
//
#include <hip/hip_runtime.h>
#include <math.h>

typedef short v8s __attribute__((ext_vector_type(8)));
typedef float v4f __attribute__((ext_vector_type(4)));

#define NVOX 64000      // 40^3
#define NPAD 74088      // 42^3
#define P2   1764       // 42^2
#define GSTR 592704     // NPAD*8
#define NCPY 32         // banked global-accumulator copies
#define ITST (NCPY*260) // stride per kmeans iteration (8320 floats)

__device__ __forceinline__ unsigned short bf16rne(float f){
  unsigned int u = __float_as_uint(f);
  u += 0x7FFFu + ((u >> 16) & 1u);
  return (unsigned short)(u >> 16);
}

// ---------------- merged prep: projection (blocks 0..999, 4-way channel split)
// + base_w bf16 repack (1000..1431) + xpt halo zeroing (1432..1471)
// + KM accumulator zeroing (1472..1553) (must precede boxdt's atomic flush).
__global__ __launch_bounds__(256) void prep_k(const float* __restrict__ x,
                                              const float* __restrict__ pw,
                                              float* __restrict__ xp,
                                              short* __restrict__ xpt,
                                              const float* __restrict__ bw,
                                              short* __restrict__ bwb,
                                              float* __restrict__ km){
  int tid = threadIdx.x;
  int bid = blockIdx.x;
  if (bid < 1000){
    int m = (bid >> 2) * 256 + tid;
    int quarter = bid & 3;
    float xv[64];
#pragma unroll
    for (int i = 0; i < 64; i++) xv[i] = x[(size_t)i * NVOX + m];
    int d = m / 1600; int r = m - d * 1600; int h = r / 40; int w = r - h * 40;
    int p = ((d + 1) * 42 + (h + 1)) * 42 + (w + 1);
    const float4* pw4 = (const float4*)pw;
    for (int g8 = quarter * 2; g8 < quarter * 2 + 2; g8++){
      v8s pk;
#pragma unroll
      for (int j = 0; j < 8; j++){
        int co = g8 * 8 + j;
        float acc = 0.f;
#pragma unroll
        for (int q = 0; q < 16; q++){
          float4 pv = pw4[co * 16 + q];   // wave-uniform -> scalar K$ loads
          acc = fmaf(pv.x, xv[4*q+0], acc);
          acc = fmaf(pv.y, xv[4*q+1], acc);
          acc = fmaf(pv.z, xv[4*q+2], acc);
          acc = fmaf(pv.w, xv[4*q+3], acc);
        }
        xp[(size_t)co * NVOX + m] = acc;
        pk[j] = (short)bf16rne(acc);
      }
      *(v8s*)(xpt + (size_t)g8 * GSTR + (size_t)p * 8) = pk;
    }
  } else if (bid < 1432){
    int e = (bid - 1000) * 256 + tid;               // 0 .. 110591
    int t5 = e >> 12; int rem = e & 4095;
    int o = rem >> 6; int c = rem & 63;
    bwb[e] = (short)bf16rne(bw[(o * 64 + c) * 27 + t5]);
  } else if (bid < 1472){
    v8s z = (v8s){0,0,0,0,0,0,0,0};
    for (int p = (bid - 1432) * 256 + tid; p < NPAD; p += 40 * 256){
      int d = p / P2; int rem = p - d * P2; int h = rem / 42; int w = rem - h * 42;
      if (d == 0 || d == 41 || h == 0 || h == 41 || w == 0 || w == 41){
#pragma unroll
        for (int g = 0; g < 8; g++)
          *(v8s*)(xpt + (size_t)g * GSTR + (size_t)p * 8) = z;
      }
    }
  } else {
    for (int j = (bid - 1472) * 256 + tid; j < 10 * ITST; j += 82 * 256)
      km[j] = 0.f;
  }
}

// ---------------- fused w+h box passes per (c,d) slice (zero pad) — R6-proven
__global__ __launch_bounds__(256) void boxwh_k(const float* __restrict__ in,
                                               float* __restrict__ out){
  __shared__ float s0[1600], s1[1600];
  size_t base = (size_t)blockIdx.x * 1600;
  int t = threadIdx.x;
  for (int e = t; e < 1600; e += 256) s0[e] = in[base + e];
  __syncthreads();
  for (int e = t; e < 1600; e += 256){
    int w = e % 40;
    float s = s0[e];
    if (w > 0)  s += s0[e - 1];
    if (w < 39) s += s0[e + 1];
    s1[e] = s;
  }
  __syncthreads();
  for (int e = t; e < 1600; e += 256){
    int h = e / 40;
    float s = s1[e];
    if (h > 0)  s += s1[e - 40];
    if (h < 39) s += s1[e + 40];
    out[base + e] = s;
  }
}

// ---------------- fused boxd + transpose + kmeans-iter0 (R10-proven).
__global__ __launch_bounds__(256) void boxdt_k(const float* __restrict__ in,
                                               float* __restrict__ out,
                                               float* __restrict__ acc1){
  __shared__ float tile[64][65];
  __shared__ float s_cent[256];
  __shared__ float s_cc[4];
  __shared__ float s_red[260];
  __shared__ int   s_kb[64];
  int t = threadIdx.x;
  int nb = blockIdx.x * 64;
  int l = t & 63, g = t >> 6;
  {
    int k = t >> 6, c = t & 63;   // cent0[k][c] = (BU2[c][k] + BU2[c][k+1600])/27 (d=0)
    s_cent[t] = (in[(size_t)c * NVOX + k] + in[(size_t)c * NVOX + k + 1600]) * (1.f / 27.f);
  }
  for (int j = t; j < 260; j += 256) s_red[j] = 0.f;
  int n = nb + l;
  int d = n / 1600;
  for (int cc = g; cc < 64; cc += 4){
    const float* b = in + (size_t)cc * NVOX + n;
    float s = b[0];
    if (d > 0)  s += b[-1600];
    if (d < 39) s += b[1600];
    tile[cc][l] = s * (1.f / 27.f);
  }
  __syncthreads();
  if (t < 4){
    float s = 0.f;
    for (int c = 0; c < 64; c++){ float v = s_cent[t * 64 + c]; s = fmaf(v, v, s); }
    s_cc[t] = s;
  }
  __syncthreads();
  if (t < 64){
    float d0 = 0.f, d1 = 0.f, d2 = 0.f, d3 = 0.f;
    for (int c = 0; c < 64; c++){
      float v = tile[c][t];
      d0 = fmaf(s_cent[c], v, d0);
      d1 = fmaf(s_cent[64 + c], v, d1);
      d2 = fmaf(s_cent[128 + c], v, d2);
      d3 = fmaf(s_cent[192 + c], v, d3);
    }
    float sc0 = s_cc[0] - 2.f * d0;
    float sc1 = s_cc[1] - 2.f * d1;
    float sc2 = s_cc[2] - 2.f * d2;
    float sc3 = s_cc[3] - 2.f * d3;
    int kb = 0; float bs = sc0;
    if (sc1 < bs){ bs = sc1; kb = 1; }
    if (sc2 < bs){ bs = sc2; kb = 2; }
    if (sc3 < bs){ bs = sc3; kb = 3; }
    s_kb[t] = kb;
  }
  __syncthreads();
  {
    int lane = t & 63, wv = t >> 6;
    float a0 = 0.f, a1 = 0.f, a2 = 0.f, a3 = 0.f;
#pragma unroll
    for (int j = 0; j < 16; j++){
      int p = wv * 16 + j;
      float v = tile[lane][p];
      int kj = s_kb[p];
      a0 += (kj == 0) ? v : 0.f;
      a1 += (kj == 1) ? v : 0.f;
      a2 += (kj == 2) ? v : 0.f;
      a3 += (kj == 3) ? v : 0.f;
    }
    atomicAdd(&s_red[lane], a0);
    atomicAdd(&s_red[64 + lane], a1);
    atomicAdd(&s_red[128 + lane], a2);
    atomicAdd(&s_red[192 + lane], a3);
  }
  if (t < 4){
    float c = 0.f;
    for (int p = 0; p < 64; p++) c += (s_kb[p] == t) ? 1.f : 0.f;
    s_red[256 + t] = c;     // single writer per slot
  }
  __syncthreads();
  float* kslot = acc1 + (blockIdx.x & (NCPY - 1)) * 260;
  for (int j = t; j < 260; j += 256) atomicAdd(&kslot[j], s_red[j]);
  for (int nn = g; nn < 64; nn += 4)
    out[(size_t)(nb + nn) * 64 + l] = tile[l][nn];
}

// ---------------- kmeans assign + reduce (iters 1..9)
__global__ __launch_bounds__(256) void assign_k(const float* __restrict__ xmt,
                                                const float* __restrict__ kin,
                                                float* __restrict__ kout){
  __shared__ float s_cent[256];
  __shared__ float s_cc[4];
  __shared__ float s_red[260];
  __shared__ float s_x[256 * 65];
  __shared__ int   s_kb[256];
  int t = threadIdx.x, lane = t & 63, wv = t >> 6;
  int n = blockIdx.x * 256 + t;
  {
    float sum = 0.f, cnt = 0.f;
#pragma unroll
    for (int s = 0; s < NCPY; s++){
      sum += kin[s * 260 + t];
      cnt += kin[s * 260 + 256 + (t >> 6)];
    }
    s_cent[t] = sum / fmaxf(cnt, 1.f);
  }
  for (int j = t; j < 260; j += 256) s_red[j] = 0.f;
  __syncthreads();
  if (t < 4){
    const float4* cc4 = (const float4*)(s_cent + t * 64);
    float s = 0.f;
#pragma unroll
    for (int q = 0; q < 16; q++){
      float4 v = cc4[q];
      s = fmaf(v.x, v.x, s); s = fmaf(v.y, v.y, s);
      s = fmaf(v.z, v.z, s); s = fmaf(v.w, v.w, s);
    }
    s_cc[t] = s;
  }
  __syncthreads();
  const float4* xt = (const float4*)(xmt + (size_t)n * 64);
  float4 xq[16];
#pragma unroll
  for (int q = 0; q < 16; q++) xq[q] = xt[q];
  float d0 = 0.f, d1 = 0.f, d2 = 0.f, d3 = 0.f;
  const float4* c4 = (const float4*)s_cent;
#pragma unroll
  for (int q = 0; q < 16; q++){
    float4 p0 = c4[q], p1 = c4[16 + q], p2 = c4[32 + q], p3 = c4[48 + q];
    d0 = fmaf(p0.x, xq[q].x, d0); d0 = fmaf(p0.y, xq[q].y, d0);
    d0 = fmaf(p0.z, xq[q].z, d0); d0 = fmaf(p0.w, xq[q].w, d0);
    d1 = fmaf(p1.x, xq[q].x, d1); d1 = fmaf(p1.y, xq[q].y, d1);
    d1 = fmaf(p1.z, xq[q].z, d1); d1 = fmaf(p1.w, xq[q].w, d1);
    d2 = fmaf(p2.x, xq[q].x, d2); d2 = fmaf(p2.y, xq[q].y, d2);
    d2 = fmaf(p2.z, xq[q].z, d2); d2 = fmaf(p2.w, xq[q].w, d2);
    d3 = fmaf(p3.x, xq[q].x, d3); d3 = fmaf(p3.y, xq[q].y, d3);
    d3 = fmaf(p3.z, xq[q].z, d3); d3 = fmaf(p3.w, xq[q].w, d3);
  }
  float sc0 = s_cc[0] - 2.f * d0;
  float sc1 = s_cc[1] - 2.f * d1;
  float sc2 = s_cc[2] - 2.f * d2;
  float sc3 = s_cc[3] - 2.f * d3;
  int kb = 0; float bs = sc0;
  if (sc1 < bs){ bs = sc1; kb = 1; }
  if (sc2 < bs){ bs = sc2; kb = 2; }
  if (sc3 < bs){ bs = sc3; kb = 3; }
  s_kb[t] = kb;
#pragma unroll
  for (int q = 0; q < 16; q++){
    s_x[t * 65 + 4*q + 0] = xq[q].x;
    s_x[t * 65 + 4*q + 1] = xq[q].y;
    s_x[t * 65 + 4*q + 2] = xq[q].z;
    s_x[t * 65 + 4*q + 3] = xq[q].w;
  }
  __syncthreads();
  float a0 = 0.f, a1 = 0.f, a2 = 0.f, a3 = 0.f;
  int rowbase = wv * 64;
#pragma unroll 16
  for (int j = 0; j < 64; j++){
    float v = s_x[(rowbase + j) * 65 + lane];
    int kj = s_kb[rowbase + j];
    a0 += (kj == 0) ? v : 0.f;
    a1 += (kj == 1) ? v : 0.f;
    a2 += (kj == 2) ? v : 0.f;
    a3 += (kj == 3) ? v : 0.f;
  }
  atomicAdd(&s_red[lane], a0);
  atomicAdd(&s_red[64 + lane], a1);
  atomicAdd(&s_red[128 + lane], a2);
  atomicAdd(&s_red[192 + lane], a3);
#pragma unroll
  for (int kk = 0; kk < 4; kk++){
    unsigned long long m = __ballot(kb == kk);
    if (lane == 0) atomicAdd(&s_red[256 + kk], (float)__popcll(m));
  }
  __syncthreads();
  float* kslot = kout + (blockIdx.x & (NCPY - 1)) * 260;
  for (int j = t; j < 260; j += 256) atomicAdd(&kslot[j], s_red[j]);
}

// ---------------- main dynamic conv + final assignment + gating MLPs.
// R13 prologue rework (vs R12): (a) xmt tile staged coalesced into LDS
// (aliased onto s_acc, dead until post-MFMA); (b) MLP layers use 4 partial
// accumulators (4x ILP) and h-path/g-path run on DISJOINT warps; summation
// order of dist/cent matches R12's verified order (c = 0..63 sequential).
__global__ __launch_bounds__(256) void conv_k(const short* __restrict__ xpt,
                                              const short* __restrict__ bwb,
                                              const float* __restrict__ km,
                                              const float* __restrict__ xmt,
                                              const float* __restrict__ x,
                                              const float* __restrict__ pa,
                                              float* __restrict__ out,
                      const float* __restrict__ w1, const float* __restrict__ b1,
                      const float* __restrict__ w2, const float* __restrict__ b2,
                      const float* __restrict__ w3, const float* __restrict__ b3,
                      const float* __restrict__ u1, const float* __restrict__ c1,
                      const float* __restrict__ u2, const float* __restrict__ c2,
                      const float* __restrict__ u3, const float* __restrict__ c3){
  static const int POFF[27] = {
    -P2-42-1, -P2-42, -P2-42+1, -P2-1, -P2, -P2+1, -P2+42-1, -P2+42, -P2+42+1,
    -42-1, -42, -42+1, -1, 0, 1, 42-1, 42, 42+1,
    P2-42-1, P2-42, P2-42+1, P2-1, P2, P2+1, P2+42-1, P2+42, P2+42+1 };
  __shared__ float s_wi[108];
  __shared__ float s_bias[256];
  __shared__ float s_acc[64 * 68];   // post-MFMA exchange; prologue aliases as s_xt[64][68]
  __shared__ float s_cent[256];
  __shared__ float s_cc[4];
  __shared__ int   s_kb[64];
  __shared__ float s_h1[128], s_h2[128], s_g1[64], s_g2[64];
  int tid = threadIdx.x;
  int vb = blockIdx.x * 64;
  // ---- cent10 (identical summation to assign_k's centroid load)
  {
    float sum = 0.f, cnt = 0.f;
#pragma unroll
    for (int s = 0; s < NCPY; s++){
      sum += km[s * 260 + tid];
      cnt += km[s * 260 + 256 + (tid >> 6)];
    }
    s_cent[tid] = sum / fmaxf(cnt, 1.f);
  }
  // ---- stage this block's 64 xmt rows into LDS, fully coalesced (16KB)
  {
    const float4* src = (const float4*)(xmt + (size_t)vb * 64);
#pragma unroll
    for (int j = tid; j < 1024; j += 256){
      float4 v = src[j];
      float* dst = s_acc + (j >> 4) * 68 + (j & 15) * 4;
      dst[0] = v.x; dst[1] = v.y; dst[2] = v.z; dst[3] = v.w;
    }
  }
  __syncthreads();
  if (tid < 4){
    const float4* cc4 = (const float4*)(s_cent + tid * 64);
    float s = 0.f;
#pragma unroll
    for (int q = 0; q < 16; q++){
      float4 v = cc4[q];
      s = fmaf(v.x, v.x, s); s = fmaf(v.y, v.y, s);
      s = fmaf(v.z, v.z, s); s = fmaf(v.w, v.w, s);
    }
    s_cc[tid] = s;
  }
  __syncthreads();
  // ---- final assignment for this block's 64 voxels (c-order matches R12)
  if (tid < 64){
    const float* xr = s_acc + tid * 68;
    float d0 = 0.f, d1 = 0.f, d2 = 0.f, d3 = 0.f;
#pragma unroll 8
    for (int c = 0; c < 64; c++){
      float v = xr[c];
      d0 = fmaf(s_cent[c], v, d0);
      d1 = fmaf(s_cent[64 + c], v, d1);
      d2 = fmaf(s_cent[128 + c], v, d2);
      d3 = fmaf(s_cent[192 + c], v, d3);
    }
    float sc0 = s_cc[0] - 2.f * d0;
    float sc1 = s_cc[1] - 2.f * d1;
    float sc2 = s_cc[2] - 2.f * d2;
    float sc3 = s_cc[3] - 2.f * d3;
    int kb = 0; float bs = sc0;
    if (sc1 < bs){ bs = sc1; kb = 1; }
    if (sc2 < bs){ bs = sc2; kb = 2; }
    if (sc3 < bs){ bs = sc3; kb = 3; }
    s_kb[tid] = kb;
  }
  // ---- gating MLPs: h-path on tid<128, g-path on tid in [128,192) (parallel)
  if (tid < 128){
    float z0 = 0.f, z1 = 0.f, z2 = 0.f, z3 = 0.f;
#pragma unroll 4
    for (int i = 0; i < 256; i += 4){
      z0 = fmaf(s_cent[i + 0], w1[(i + 0) * 128 + tid], z0);
      z1 = fmaf(s_cent[i + 1], w1[(i + 1) * 128 + tid], z1);
      z2 = fmaf(s_cent[i + 2], w1[(i + 2) * 128 + tid], z2);
      z3 = fmaf(s_cent[i + 3], w1[(i + 3) * 128 + tid], z3);
    }
    s_h1[tid] = fmaxf(b1[tid] + ((z0 + z1) + (z2 + z3)), 0.f);
  } else if (tid < 192){
    int t6 = tid - 128;
    float z0 = 0.f, z1 = 0.f, z2 = 0.f, z3 = 0.f;
#pragma unroll 4
    for (int i = 0; i < 256; i += 4){
      z0 = fmaf(s_cent[i + 0], u1[(i + 0) * 64 + t6], z0);
      z1 = fmaf(s_cent[i + 1], u1[(i + 1) * 64 + t6], z1);
      z2 = fmaf(s_cent[i + 2], u1[(i + 2) * 64 + t6], z2);
      z3 = fmaf(s_cent[i + 3], u1[(i + 3) * 64 + t6], z3);
    }
    s_g1[t6] = fmaxf(c1[t6] + ((z0 + z1) + (z2 + z3)), 0.f);
  }
  __syncthreads();
  if (tid < 128){
    float z0 = 0.f, z1 = 0.f, z2 = 0.f, z3 = 0.f;
#pragma unroll 4
    for (int i = 0; i < 128; i += 4){
      z0 = fmaf(s_h1[i + 0], w2[(i + 0) * 128 + tid], z0);
      z1 = fmaf(s_h1[i + 1], w2[(i + 1) * 128 + tid], z1);
      z2 = fmaf(s_h1[i + 2], w2[(i + 2) * 128 + tid], z2);
      z3 = fmaf(s_h1[i + 3], w2[(i + 3) * 128 + tid], z3);
    }
    s_h2[tid] = fmaxf(b2[tid] + ((z0 + z1) + (z2 + z3)), 0.f);
  } else if (tid < 192){
    int t6 = tid - 128;
    float z0 = 0.f, z1 = 0.f, z2 = 0.f, z3 = 0.f;
#pragma unroll 4
    for (int i = 0; i < 64; i += 4){
      z0 = fmaf(s_g1[i + 0], u2[(i + 0) * 64 + t6], z0);
      z1 = fmaf(s_g1[i + 1], u2[(i + 1) * 64 + t6], z1);
      z2 = fmaf(s_g1[i + 2], u2[(i + 2) * 64 + t6], z2);
      z3 = fmaf(s_g1[i + 3], u2[(i + 3) * 64 + t6], z3);
    }
    s_g2[t6] = fmaxf(c2[t6] + ((z0 + z1) + (z2 + z3)), 0.f);
  }
  __syncthreads();
  if (tid < 108){
    float z0 = 0.f, z1 = 0.f, z2 = 0.f, z3 = 0.f;
#pragma unroll 4
    for (int i = 0; i < 128; i += 4){
      z0 = fmaf(s_h2[i + 0], w3[(i + 0) * 108 + tid], z0);
      z1 = fmaf(s_h2[i + 1], w3[(i + 1) * 108 + tid], z1);
      z2 = fmaf(s_h2[i + 2], w3[(i + 2) * 108 + tid], z2);
      z3 = fmaf(s_h2[i + 3], w3[(i + 3) * 108 + tid], z3);
    }
    float z = b3[tid] + ((z0 + z1) + (z2 + z3));
    s_wi[tid] = 1.f / (1.f + expf(-z));
  }
  {
    float z0 = 0.f, z1 = 0.f, z2 = 0.f, z3 = 0.f;
#pragma unroll 4
    for (int i = 0; i < 64; i += 4){
      z0 = fmaf(s_g2[i + 0], u3[(i + 0) * 256 + tid], z0);
      z1 = fmaf(s_g2[i + 1], u3[(i + 1) * 256 + tid], z1);
      z2 = fmaf(s_g2[i + 2], u3[(i + 2) * 256 + tid], z2);
      z3 = fmaf(s_g2[i + 3], u3[(i + 3) * 256 + tid], z3);
    }
    s_bias[tid] = c3[tid] + ((z0 + z1) + (z2 + z3));
  }
  __syncthreads();
  // ---- conv proper (R6-verbatim)
  int wv = tid >> 6, lane = tid & 63;
  int kc = wv & 1, mh = wv >> 1;
  int col = lane & 15, kg = lane >> 4;
  int p4[4], ki4[4];
#pragma unroll
  for (int nt = 0; nt < 4; nt++){
    int v = vb + nt * 16 + col;
    ki4[nt] = s_kb[nt * 16 + col];
    int d = v / 1600; int r = v - d * 1600; int h = r / 40; int w = r - h * 40;
    p4[nt] = ((d + 1) * 42 + (h + 1)) * 42 + (w + 1);
  }
  const short* bg = xpt + (size_t)(kc * 4 + kg) * GSTR;
  const short* bp0 = bg + (size_t)p4[0] * 8;
  const short* bp1 = bg + (size_t)p4[1] * 8;
  const short* bp2 = bg + (size_t)p4[2] * 8;
  const short* bp3 = bg + (size_t)p4[3] * 8;
  int ao0 = (mh * 32 + col) * 64 + kc * 32 + kg * 8;
  int ao1 = ao0 + 16 * 64;
  v4f acc[2][4];
#pragma unroll
  for (int m2 = 0; m2 < 2; m2++)
#pragma unroll
    for (int nt = 0; nt < 4; nt++) acc[m2][nt] = (v4f){0.f, 0.f, 0.f, 0.f};
  v4f zero = {0.f, 0.f, 0.f, 0.f};
#pragma unroll 9
  for (int t = 0; t < 27; t++){
    int po8 = POFF[t] * 8;
    v8s a0 = *(const v8s*)(bwb + t * 4096 + ao0);
    v8s a1 = *(const v8s*)(bwb + t * 4096 + ao1);
    v8s b0 = *(const v8s*)(bp0 + po8);
    v8s b1 = *(const v8s*)(bp1 + po8);
    v8s b2 = *(const v8s*)(bp2 + po8);
    v8s b3 = *(const v8s*)(bp3 + po8);
    float wk0 = s_wi[ki4[0] * 27 + t];
    float wk1 = s_wi[ki4[1] * 27 + t];
    float wk2 = s_wi[ki4[2] * 27 + t];
    float wk3 = s_wi[ki4[3] * 27 + t];
    v4f tp;
    tp = __builtin_amdgcn_mfma_f32_16x16x32_bf16(a0, b0, zero, 0, 0, 0); acc[0][0] += tp * wk0;
    tp = __builtin_amdgcn_mfma_f32_16x16x32_bf16(a1, b0, zero, 0, 0, 0); acc[1][0] += tp * wk0;
    tp = __builtin_amdgcn_mfma_f32_16x16x32_bf16(a0, b1, zero, 0, 0, 0); acc[0][1] += tp * wk1;
    tp = __builtin_amdgcn_mfma_f32_16x16x32_bf16(a1, b1, zero, 0, 0, 0); acc[1][1] += tp * wk1;
    tp = __builtin_amdgcn_mfma_f32_16x16x32_bf16(a0, b2, zero, 0, 0, 0); acc[0][2] += tp * wk2;
    tp = __builtin_amdgcn_mfma_f32_16x16x32_bf16(a1, b2, zero, 0, 0, 0); acc[1][2] += tp * wk2;
    tp = __builtin_amdgcn_mfma_f32_16x16x32_bf16(a0, b3, zero, 0, 0, 0); acc[0][3] += tp * wk3;
    tp = __builtin_amdgcn_mfma_f32_16x16x32_bf16(a1, b3, zero, 0, 0, 0); acc[1][3] += tp * wk3;
  }
  __syncthreads();
  if (kc == 1){
#pragma unroll
    for (int m2 = 0; m2 < 2; m2++)
#pragma unroll
      for (int nt = 0; nt < 4; nt++)
        *(v4f*)(&s_acc[(nt * 16 + col) * 68 + mh * 32 + m2 * 16 + kg * 4]) = acc[m2][nt];
  }
  __syncthreads();
  if (kc == 0){
    float pav = pa[0];
#pragma unroll
    for (int m2 = 0; m2 < 2; m2++){
#pragma unroll
      for (int nt = 0; nt < 4; nt++){
        v4f other = *(const v4f*)(&s_acc[(nt * 16 + col) * 68 + mh * 32 + m2 * 16 + kg * 4]);
        v4f sum = acc[m2][nt] + other;
        int n = vb + nt * 16 + col;
#pragma unroll
        for (int r = 0; r < 4; r++){
          int o = mh * 32 + m2 * 16 + kg * 4 + r;
          float val = sum[r] + s_bias[ki4[nt] * 64 + o];
          val = (val >= 0.f) ? val : pav * val;
          size_t off = (size_t)o * NVOX + n;
          out[off] = val + x[off];
        }
      }
    }
  }
}

extern "C" void kernel_launch(void* const* d_in, const int* in_sizes, int n_in,
                              void* d_out, int out_size, void* d_ws, size_t ws_size,
                              hipStream_t stream){
  const float* x    = (const float*)d_in[0];
  const float* pw   = (const float*)d_in[1];
  const float* bw   = (const float*)d_in[2];
  const float* gkw1 = (const float*)d_in[3];
  const float* gkb1 = (const float*)d_in[4];
  const float* gkw2 = (const float*)d_in[5];
  const float* gkb2 = (const float*)d_in[6];
  const float* gkw3 = (const float*)d_in[7];
  const float* gkb3 = (const float*)d_in[8];
  const float* gbw1 = (const float*)d_in[9];
  const float* gbb1 = (const float*)d_in[10];
  const float* gbw2 = (const float*)d_in[11];
  const float* gbb2 = (const float*)d_in[12];
  const float* gbw3 = (const float*)d_in[13];
  const float* gbb3 = (const float*)d_in[14];
  const float* pa   = (const float*)d_in[15];
  float* outp = (float*)d_out;

  float* ws   = (float*)d_ws;
  float* XP   = ws;                                  // 4,096,000 f ; reused as XMT
  float* BU2  = ws + 4096000;                        // 4,096,000 f (wh-filtered)
  short* XPT  = (short*)(ws + 12288000);             // 4,741,632 s
  short* BWB  = XPT + (size_t)NPAD * 64;             // 110,592 s
  float* KM   = (float*)(BWB + 110592);              // 10*8320 f  (ACC[1..10])
  float* XMT  = XP;                                  // xm transposed [n][c]

  prep_k<<<1554, 256, 0, stream>>>(x, pw, XP, XPT, bw, BWB, KM);
  boxwh_k<<<2560, 256, 0, stream>>>(XP, BU2);
  boxdt_k<<<1000, 256, 0, stream>>>(BU2, XMT, KM);
  for (int it = 1; it <= 9; it++)
    assign_k<<<250, 256, 0, stream>>>(XMT, KM + (it - 1) * ITST, KM + it * ITST);
  conv_k<<<1000, 256, 0, stream>>>(XPT, BWB, KM + 9 * ITST, XMT, x, pa, outp,
                                   gkw1, gkb1, gkw2, gkb2, gkw3, gkb3,
                                   gbw1, gbb1, gbw2, gbb2, gbw3, gbb3);
}

// Round 14
// 300.619 us; speedup vs baseline: 1.1586x; 1.0133x over previous
//
#include <hip/hip_runtime.h>
#include <math.h>

typedef short v8s __attribute__((ext_vector_type(8)));
typedef float v4f __attribute__((ext_vector_type(4)));

#define NVOX 64000      // 40^3
#define NPAD 74088      // 42^3
#define P2   1764       // 42^2
#define GSTR 592704     // NPAD*8
#define NCPY 32         // banked global-accumulator copies
#define ITST (NCPY*260) // stride per kmeans iteration (8320 floats)

__device__ __forceinline__ unsigned short bf16rne(float f){
  unsigned int u = __float_as_uint(f);
  u += 0x7FFFu + ((u >> 16) & 1u);
  return (unsigned short)(u >> 16);
}

// ---------------- merged prep: projection (blocks 0..999, 4-way channel split)
// + base_w bf16 repack (1000..1431) + xpt halo zeroing (1432..1471)
// + KM accumulator zeroing (1472..1553) (must precede boxdt's atomic flush).
__global__ __launch_bounds__(256) void prep_k(const float* __restrict__ x,
                                              const float* __restrict__ pw,
                                              float* __restrict__ xp,
                                              short* __restrict__ xpt,
                                              const float* __restrict__ bw,
                                              short* __restrict__ bwb,
                                              float* __restrict__ km){
  int tid = threadIdx.x;
  int bid = blockIdx.x;
  if (bid < 1000){
    int m = (bid >> 2) * 256 + tid;
    int quarter = bid & 3;
    float xv[64];
#pragma unroll
    for (int i = 0; i < 64; i++) xv[i] = x[(size_t)i * NVOX + m];
    int d = m / 1600; int r = m - d * 1600; int h = r / 40; int w = r - h * 40;
    int p = ((d + 1) * 42 + (h + 1)) * 42 + (w + 1);
    const float4* pw4 = (const float4*)pw;
    for (int g8 = quarter * 2; g8 < quarter * 2 + 2; g8++){
      v8s pk;
#pragma unroll
      for (int j = 0; j < 8; j++){
        int co = g8 * 8 + j;
        float acc = 0.f;
#pragma unroll
        for (int q = 0; q < 16; q++){
          float4 pv = pw4[co * 16 + q];   // wave-uniform -> scalar K$ loads
          acc = fmaf(pv.x, xv[4*q+0], acc);
          acc = fmaf(pv.y, xv[4*q+1], acc);
          acc = fmaf(pv.z, xv[4*q+2], acc);
          acc = fmaf(pv.w, xv[4*q+3], acc);
        }
        xp[(size_t)co * NVOX + m] = acc;
        pk[j] = (short)bf16rne(acc);
      }
      *(v8s*)(xpt + (size_t)g8 * GSTR + (size_t)p * 8) = pk;
    }
  } else if (bid < 1432){
    int e = (bid - 1000) * 256 + tid;               // 0 .. 110591
    int t5 = e >> 12; int rem = e & 4095;
    int o = rem >> 6; int c = rem & 63;
    bwb[e] = (short)bf16rne(bw[(o * 64 + c) * 27 + t5]);
  } else if (bid < 1472){
    v8s z = (v8s){0,0,0,0,0,0,0,0};
    for (int p = (bid - 1432) * 256 + tid; p < NPAD; p += 40 * 256){
      int d = p / P2; int rem = p - d * P2; int h = rem / 42; int w = rem - h * 42;
      if (d == 0 || d == 41 || h == 0 || h == 41 || w == 0 || w == 41){
#pragma unroll
        for (int g = 0; g < 8; g++)
          *(v8s*)(xpt + (size_t)g * GSTR + (size_t)p * 8) = z;
      }
    }
  } else {
    for (int j = (bid - 1472) * 256 + tid; j < 10 * ITST; j += 82 * 256)
      km[j] = 0.f;
  }
}

// ---------------- fused w+h box passes per (c,d) slice (zero pad) — R6-proven
__global__ __launch_bounds__(256) void boxwh_k(const float* __restrict__ in,
                                               float* __restrict__ out){
  __shared__ float s0[1600], s1[1600];
  size_t base = (size_t)blockIdx.x * 1600;
  int t = threadIdx.x;
  for (int e = t; e < 1600; e += 256) s0[e] = in[base + e];
  __syncthreads();
  for (int e = t; e < 1600; e += 256){
    int w = e % 40;
    float s = s0[e];
    if (w > 0)  s += s0[e - 1];
    if (w < 39) s += s0[e + 1];
    s1[e] = s;
  }
  __syncthreads();
  for (int e = t; e < 1600; e += 256){
    int h = e / 40;
    float s = s1[e];
    if (h > 0)  s += s1[e - 40];
    if (h < 39) s += s1[e + 40];
    out[base + e] = s;
  }
}

// ---------------- fused boxd + transpose + kmeans-iter0 (R10-proven).
__global__ __launch_bounds__(256) void boxdt_k(const float* __restrict__ in,
                                               float* __restrict__ out,
                                               float* __restrict__ acc1){
  __shared__ float tile[64][65];
  __shared__ float s_cent[256];
  __shared__ float s_cc[4];
  __shared__ float s_red[260];
  __shared__ int   s_kb[64];
  int t = threadIdx.x;
  int nb = blockIdx.x * 64;
  int l = t & 63, g = t >> 6;
  {
    int k = t >> 6, c = t & 63;   // cent0[k][c] = (BU2[c][k] + BU2[c][k+1600])/27 (d=0)
    s_cent[t] = (in[(size_t)c * NVOX + k] + in[(size_t)c * NVOX + k + 1600]) * (1.f / 27.f);
  }
  for (int j = t; j < 260; j += 256) s_red[j] = 0.f;
  int n = nb + l;
  int d = n / 1600;
  for (int cc = g; cc < 64; cc += 4){
    const float* b = in + (size_t)cc * NVOX + n;
    float s = b[0];
    if (d > 0)  s += b[-1600];
    if (d < 39) s += b[1600];
    tile[cc][l] = s * (1.f / 27.f);
  }
  __syncthreads();
  if (t < 4){
    float s = 0.f;
    for (int c = 0; c < 64; c++){ float v = s_cent[t * 64 + c]; s = fmaf(v, v, s); }
    s_cc[t] = s;
  }
  __syncthreads();
  if (t < 64){
    float d0 = 0.f, d1 = 0.f, d2 = 0.f, d3 = 0.f;
    for (int c = 0; c < 64; c++){
      float v = tile[c][t];
      d0 = fmaf(s_cent[c], v, d0);
      d1 = fmaf(s_cent[64 + c], v, d1);
      d2 = fmaf(s_cent[128 + c], v, d2);
      d3 = fmaf(s_cent[192 + c], v, d3);
    }
    float sc0 = s_cc[0] - 2.f * d0;
    float sc1 = s_cc[1] - 2.f * d1;
    float sc2 = s_cc[2] - 2.f * d2;
    float sc3 = s_cc[3] - 2.f * d3;
    int kb = 0; float bs = sc0;
    if (sc1 < bs){ bs = sc1; kb = 1; }
    if (sc2 < bs){ bs = sc2; kb = 2; }
    if (sc3 < bs){ bs = sc3; kb = 3; }
    s_kb[t] = kb;
  }
  __syncthreads();
  {
    int lane = t & 63, wv = t >> 6;
    float a0 = 0.f, a1 = 0.f, a2 = 0.f, a3 = 0.f;
#pragma unroll
    for (int j = 0; j < 16; j++){
      int p = wv * 16 + j;
      float v = tile[lane][p];
      int kj = s_kb[p];
      a0 += (kj == 0) ? v : 0.f;
      a1 += (kj == 1) ? v : 0.f;
      a2 += (kj == 2) ? v : 0.f;
      a3 += (kj == 3) ? v : 0.f;
    }
    atomicAdd(&s_red[lane], a0);
    atomicAdd(&s_red[64 + lane], a1);
    atomicAdd(&s_red[128 + lane], a2);
    atomicAdd(&s_red[192 + lane], a3);
  }
  if (t < 4){
    float c = 0.f;
    for (int p = 0; p < 64; p++) c += (s_kb[p] == t) ? 1.f : 0.f;
    s_red[256 + t] = c;     // single writer per slot
  }
  __syncthreads();
  float* kslot = acc1 + (blockIdx.x & (NCPY - 1)) * 260;
  for (int j = t; j < 260; j += 256) atomicAdd(&kslot[j], s_red[j]);
  for (int nn = g; nn < 64; nn += 4)
    out[(size_t)(nb + nn) * 64 + l] = tile[l][nn];
}

// ---------------- kmeans assign + reduce (iters 1..9)
__global__ __launch_bounds__(256) void assign_k(const float* __restrict__ xmt,
                                                const float* __restrict__ kin,
                                                float* __restrict__ kout){
  __shared__ float s_cent[256];
  __shared__ float s_cc[4];
  __shared__ float s_red[260];
  __shared__ float s_x[256 * 65];
  __shared__ int   s_kb[256];
  int t = threadIdx.x, lane = t & 63, wv = t >> 6;
  int n = blockIdx.x * 256 + t;
  {
    float sum = 0.f, cnt = 0.f;
#pragma unroll
    for (int s = 0; s < NCPY; s++){
      sum += kin[s * 260 + t];
      cnt += kin[s * 260 + 256 + (t >> 6)];
    }
    s_cent[t] = sum / fmaxf(cnt, 1.f);
  }
  for (int j = t; j < 260; j += 256) s_red[j] = 0.f;
  __syncthreads();
  if (t < 4){
    const float4* cc4 = (const float4*)(s_cent + t * 64);
    float s = 0.f;
#pragma unroll
    for (int q = 0; q < 16; q++){
      float4 v = cc4[q];
      s = fmaf(v.x, v.x, s); s = fmaf(v.y, v.y, s);
      s = fmaf(v.z, v.z, s); s = fmaf(v.w, v.w, s);
    }
    s_cc[t] = s;
  }
  __syncthreads();
  const float4* xt = (const float4*)(xmt + (size_t)n * 64);
  float4 xq[16];
#pragma unroll
  for (int q = 0; q < 16; q++) xq[q] = xt[q];
  float d0 = 0.f, d1 = 0.f, d2 = 0.f, d3 = 0.f;
  const float4* c4 = (const float4*)s_cent;
#pragma unroll
  for (int q = 0; q < 16; q++){
    float4 p0 = c4[q], p1 = c4[16 + q], p2 = c4[32 + q], p3 = c4[48 + q];
    d0 = fmaf(p0.x, xq[q].x, d0); d0 = fmaf(p0.y, xq[q].y, d0);
    d0 = fmaf(p0.z, xq[q].z, d0); d0 = fmaf(p0.w, xq[q].w, d0);
    d1 = fmaf(p1.x, xq[q].x, d1); d1 = fmaf(p1.y, xq[q].y, d1);
    d1 = fmaf(p1.z, xq[q].z, d1); d1 = fmaf(p1.w, xq[q].w, d1);
    d2 = fmaf(p2.x, xq[q].x, d2); d2 = fmaf(p2.y, xq[q].y, d2);
    d2 = fmaf(p2.z, xq[q].z, d2); d2 = fmaf(p2.w, xq[q].w, d2);
    d3 = fmaf(p3.x, xq[q].x, d3); d3 = fmaf(p3.y, xq[q].y, d3);
    d3 = fmaf(p3.z, xq[q].z, d3); d3 = fmaf(p3.w, xq[q].w, d3);
  }
  float sc0 = s_cc[0] - 2.f * d0;
  float sc1 = s_cc[1] - 2.f * d1;
  float sc2 = s_cc[2] - 2.f * d2;
  float sc3 = s_cc[3] - 2.f * d3;
  int kb = 0; float bs = sc0;
  if (sc1 < bs){ bs = sc1; kb = 1; }
  if (sc2 < bs){ bs = sc2; kb = 2; }
  if (sc3 < bs){ bs = sc3; kb = 3; }
  s_kb[t] = kb;
#pragma unroll
  for (int q = 0; q < 16; q++){
    s_x[t * 65 + 4*q + 0] = xq[q].x;
    s_x[t * 65 + 4*q + 1] = xq[q].y;
    s_x[t * 65 + 4*q + 2] = xq[q].z;
    s_x[t * 65 + 4*q + 3] = xq[q].w;
  }
  __syncthreads();
  float a0 = 0.f, a1 = 0.f, a2 = 0.f, a3 = 0.f;
  int rowbase = wv * 64;
#pragma unroll 16
  for (int j = 0; j < 64; j++){
    float v = s_x[(rowbase + j) * 65 + lane];
    int kj = s_kb[rowbase + j];
    a0 += (kj == 0) ? v : 0.f;
    a1 += (kj == 1) ? v : 0.f;
    a2 += (kj == 2) ? v : 0.f;
    a3 += (kj == 3) ? v : 0.f;
  }
  atomicAdd(&s_red[lane], a0);
  atomicAdd(&s_red[64 + lane], a1);
  atomicAdd(&s_red[128 + lane], a2);
  atomicAdd(&s_red[192 + lane], a3);
#pragma unroll
  for (int kk = 0; kk < 4; kk++){
    unsigned long long m = __ballot(kb == kk);
    if (lane == 0) atomicAdd(&s_red[256 + kk], (float)__popcll(m));
  }
  __syncthreads();
  float* kslot = kout + (blockIdx.x & (NCPY - 1)) * 260;
  for (int j = t; j < 260; j += 256) atomicAdd(&kslot[j], s_red[j]);
}

// ---------------- finalize: cent10 -> idx (all blocks) + gating MLPs (block 0,
// R13-parallelized: 4-acc ILP, h-path/g-path on disjoint warps). Replaces the
// R11 mode-1 assign whose block-0 serial MLP chains cost ~30us of wall.
__global__ __launch_bounds__(256) void fin_k(const float* __restrict__ xmt,
                                             const float* __restrict__ kin,
                                             int* __restrict__ idx,
                      const float* __restrict__ w1, const float* __restrict__ b1,
                      const float* __restrict__ w2, const float* __restrict__ b2,
                      const float* __restrict__ w3, const float* __restrict__ b3,
                      const float* __restrict__ u1, const float* __restrict__ c1,
                      const float* __restrict__ u2, const float* __restrict__ c2,
                      const float* __restrict__ u3, const float* __restrict__ c3,
                      float* __restrict__ wi, float* __restrict__ bias){
  __shared__ float s_cent[256];
  __shared__ float s_cc[4];
  __shared__ float s_h1[128], s_h2[128], s_g1[64], s_g2[64];
  int t = threadIdx.x;
  int n = blockIdx.x * 256 + t;
  {
    float sum = 0.f, cnt = 0.f;
#pragma unroll
    for (int s = 0; s < NCPY; s++){
      sum += kin[s * 260 + t];
      cnt += kin[s * 260 + 256 + (t >> 6)];
    }
    s_cent[t] = sum / fmaxf(cnt, 1.f);
  }
  __syncthreads();
  if (t < 4){
    const float4* cc4 = (const float4*)(s_cent + t * 64);
    float s = 0.f;
#pragma unroll
    for (int q = 0; q < 16; q++){
      float4 v = cc4[q];
      s = fmaf(v.x, v.x, s); s = fmaf(v.y, v.y, s);
      s = fmaf(v.z, v.z, s); s = fmaf(v.w, v.w, s);
    }
    s_cc[t] = s;
  }
  __syncthreads();
  {
    const float4* xt = (const float4*)(xmt + (size_t)n * 64);
    float4 xq[16];
#pragma unroll
    for (int q = 0; q < 16; q++) xq[q] = xt[q];
    float d0 = 0.f, d1 = 0.f, d2 = 0.f, d3 = 0.f;
    const float4* c4 = (const float4*)s_cent;
#pragma unroll
    for (int q = 0; q < 16; q++){
      float4 p0 = c4[q], p1 = c4[16 + q], p2 = c4[32 + q], p3 = c4[48 + q];
      d0 = fmaf(p0.x, xq[q].x, d0); d0 = fmaf(p0.y, xq[q].y, d0);
      d0 = fmaf(p0.z, xq[q].z, d0); d0 = fmaf(p0.w, xq[q].w, d0);
      d1 = fmaf(p1.x, xq[q].x, d1); d1 = fmaf(p1.y, xq[q].y, d1);
      d1 = fmaf(p1.z, xq[q].z, d1); d1 = fmaf(p1.w, xq[q].w, d1);
      d2 = fmaf(p2.x, xq[q].x, d2); d2 = fmaf(p2.y, xq[q].y, d2);
      d2 = fmaf(p2.z, xq[q].z, d2); d2 = fmaf(p2.w, xq[q].w, d2);
      d3 = fmaf(p3.x, xq[q].x, d3); d3 = fmaf(p3.y, xq[q].y, d3);
      d3 = fmaf(p3.z, xq[q].z, d3); d3 = fmaf(p3.w, xq[q].w, d3);
    }
    float sc0 = s_cc[0] - 2.f * d0;
    float sc1 = s_cc[1] - 2.f * d1;
    float sc2 = s_cc[2] - 2.f * d2;
    float sc3 = s_cc[3] - 2.f * d3;
    int kb = 0; float bs = sc0;
    if (sc1 < bs){ bs = sc1; kb = 1; }
    if (sc2 < bs){ bs = sc2; kb = 2; }
    if (sc3 < bs){ bs = sc3; kb = 3; }
    idx[n] = kb;
  }
  if (blockIdx.x != 0) return;
  // ---- gating MLPs (R13-verified parallel form)
  if (t < 128){
    float z0 = 0.f, z1 = 0.f, z2 = 0.f, z3 = 0.f;
#pragma unroll 4
    for (int i = 0; i < 256; i += 4){
      z0 = fmaf(s_cent[i + 0], w1[(i + 0) * 128 + t], z0);
      z1 = fmaf(s_cent[i + 1], w1[(i + 1) * 128 + t], z1);
      z2 = fmaf(s_cent[i + 2], w1[(i + 2) * 128 + t], z2);
      z3 = fmaf(s_cent[i + 3], w1[(i + 3) * 128 + t], z3);
    }
    s_h1[t] = fmaxf(b1[t] + ((z0 + z1) + (z2 + z3)), 0.f);
  } else if (t < 192){
    int t6 = t - 128;
    float z0 = 0.f, z1 = 0.f, z2 = 0.f, z3 = 0.f;
#pragma unroll 4
    for (int i = 0; i < 256; i += 4){
      z0 = fmaf(s_cent[i + 0], u1[(i + 0) * 64 + t6], z0);
      z1 = fmaf(s_cent[i + 1], u1[(i + 1) * 64 + t6], z1);
      z2 = fmaf(s_cent[i + 2], u1[(i + 2) * 64 + t6], z2);
      z3 = fmaf(s_cent[i + 3], u1[(i + 3) * 64 + t6], z3);
    }
    s_g1[t6] = fmaxf(c1[t6] + ((z0 + z1) + (z2 + z3)), 0.f);
  }
  __syncthreads();
  if (t < 128){
    float z0 = 0.f, z1 = 0.f, z2 = 0.f, z3 = 0.f;
#pragma unroll 4
    for (int i = 0; i < 128; i += 4){
      z0 = fmaf(s_h1[i + 0], w2[(i + 0) * 128 + t], z0);
      z1 = fmaf(s_h1[i + 1], w2[(i + 1) * 128 + t], z1);
      z2 = fmaf(s_h1[i + 2], w2[(i + 2) * 128 + t], z2);
      z3 = fmaf(s_h1[i + 3], w2[(i + 3) * 128 + t], z3);
    }
    s_h2[t] = fmaxf(b2[t] + ((z0 + z1) + (z2 + z3)), 0.f);
  } else if (t < 192){
    int t6 = t - 128;
    float z0 = 0.f, z1 = 0.f, z2 = 0.f, z3 = 0.f;
#pragma unroll 4
    for (int i = 0; i < 64; i += 4){
      z0 = fmaf(s_g1[i + 0], u2[(i + 0) * 64 + t6], z0);
      z1 = fmaf(s_g1[i + 1], u2[(i + 1) * 64 + t6], z1);
      z2 = fmaf(s_g1[i + 2], u2[(i + 2) * 64 + t6], z2);
      z3 = fmaf(s_g1[i + 3], u2[(i + 3) * 64 + t6], z3);
    }
    s_g2[t6] = fmaxf(c2[t6] + ((z0 + z1) + (z2 + z3)), 0.f);
  }
  __syncthreads();
  if (t < 108){
    float z0 = 0.f, z1 = 0.f, z2 = 0.f, z3 = 0.f;
#pragma unroll 4
    for (int i = 0; i < 128; i += 4){
      z0 = fmaf(s_h2[i + 0], w3[(i + 0) * 108 + t], z0);
      z1 = fmaf(s_h2[i + 1], w3[(i + 1) * 108 + t], z1);
      z2 = fmaf(s_h2[i + 2], w3[(i + 2) * 108 + t], z2);
      z3 = fmaf(s_h2[i + 3], w3[(i + 3) * 108 + t], z3);
    }
    float z = b3[t] + ((z0 + z1) + (z2 + z3));
    wi[t] = 1.f / (1.f + expf(-z));
  }
  {
    float z0 = 0.f, z1 = 0.f, z2 = 0.f, z3 = 0.f;
#pragma unroll 4
    for (int i = 0; i < 64; i += 4){
      z0 = fmaf(s_g2[i + 0], u3[(i + 0) * 256 + t], z0);
      z1 = fmaf(s_g2[i + 1], u3[(i + 1) * 256 + t], z1);
      z2 = fmaf(s_g2[i + 2], u3[(i + 2) * 256 + t], z2);
      z3 = fmaf(s_g2[i + 3], u3[(i + 3) * 256 + t], z3);
    }
    bias[t] = c3[t] + ((z0 + z1) + (z2 + z3));
  }
}

// ---------------- main dynamic conv (R6-verbatim, proven 49us / 28MB FETCH).
__global__ __launch_bounds__(256) void conv_k(const short* __restrict__ xpt,
                                              const short* __restrict__ bwb,
                                              const float* __restrict__ wi,
                                              const float* __restrict__ bias,
                                              const int* __restrict__ idx,
                                              const float* __restrict__ x,
                                              const float* __restrict__ pa,
                                              float* __restrict__ out){
  static const int POFF[27] = {
    -P2-42-1, -P2-42, -P2-42+1, -P2-1, -P2, -P2+1, -P2+42-1, -P2+42, -P2+42+1,
    -42-1, -42, -42+1, -1, 0, 1, 42-1, 42, 42+1,
    P2-42-1, P2-42, P2-42+1, P2-1, P2, P2+1, P2+42-1, P2+42, P2+42+1 };
  __shared__ float s_wi[108];
  __shared__ float s_bias[256];
  __shared__ float s_acc[64 * 68];
  int tid = threadIdx.x;
  for (int j = tid; j < 108; j += 256) s_wi[j] = wi[j];
  s_bias[tid] = bias[tid];
  __syncthreads();
  int wv = tid >> 6, lane = tid & 63;
  int kc = wv & 1, mh = wv >> 1;
  int col = lane & 15, kg = lane >> 4;
  int vb = blockIdx.x * 64;
  int p4[4], ki4[4];
#pragma unroll
  for (int nt = 0; nt < 4; nt++){
    int v = vb + nt * 16 + col;
    ki4[nt] = idx[v];
    int d = v / 1600; int r = v - d * 1600; int h = r / 40; int w = r - h * 40;
    p4[nt] = ((d + 1) * 42 + (h + 1)) * 42 + (w + 1);
  }
  const short* bg = xpt + (size_t)(kc * 4 + kg) * GSTR;
  const short* bp0 = bg + (size_t)p4[0] * 8;
  const short* bp1 = bg + (size_t)p4[1] * 8;
  const short* bp2 = bg + (size_t)p4[2] * 8;
  const short* bp3 = bg + (size_t)p4[3] * 8;
  int ao0 = (mh * 32 + col) * 64 + kc * 32 + kg * 8;
  int ao1 = ao0 + 16 * 64;
  v4f acc[2][4];
#pragma unroll
  for (int m2 = 0; m2 < 2; m2++)
#pragma unroll
    for (int nt = 0; nt < 4; nt++) acc[m2][nt] = (v4f){0.f, 0.f, 0.f, 0.f};
  v4f zero = {0.f, 0.f, 0.f, 0.f};
#pragma unroll 9
  for (int t = 0; t < 27; t++){
    int po8 = POFF[t] * 8;
    v8s a0 = *(const v8s*)(bwb + t * 4096 + ao0);
    v8s a1 = *(const v8s*)(bwb + t * 4096 + ao1);
    v8s b0 = *(const v8s*)(bp0 + po8);
    v8s b1 = *(const v8s*)(bp1 + po8);
    v8s b2 = *(const v8s*)(bp2 + po8);
    v8s b3 = *(const v8s*)(bp3 + po8);
    float wk0 = s_wi[ki4[0] * 27 + t];
    float wk1 = s_wi[ki4[1] * 27 + t];
    float wk2 = s_wi[ki4[2] * 27 + t];
    float wk3 = s_wi[ki4[3] * 27 + t];
    v4f tp;
    tp = __builtin_amdgcn_mfma_f32_16x16x32_bf16(a0, b0, zero, 0, 0, 0); acc[0][0] += tp * wk0;
    tp = __builtin_amdgcn_mfma_f32_16x16x32_bf16(a1, b0, zero, 0, 0, 0); acc[1][0] += tp * wk0;
    tp = __builtin_amdgcn_mfma_f32_16x16x32_bf16(a0, b1, zero, 0, 0, 0); acc[0][1] += tp * wk1;
    tp = __builtin_amdgcn_mfma_f32_16x16x32_bf16(a1, b1, zero, 0, 0, 0); acc[1][1] += tp * wk1;
    tp = __builtin_amdgcn_mfma_f32_16x16x32_bf16(a0, b2, zero, 0, 0, 0); acc[0][2] += tp * wk2;
    tp = __builtin_amdgcn_mfma_f32_16x16x32_bf16(a1, b2, zero, 0, 0, 0); acc[1][2] += tp * wk2;
    tp = __builtin_amdgcn_mfma_f32_16x16x32_bf16(a0, b3, zero, 0, 0, 0); acc[0][3] += tp * wk3;
    tp = __builtin_amdgcn_mfma_f32_16x16x32_bf16(a1, b3, zero, 0, 0, 0); acc[1][3] += tp * wk3;
  }
  __syncthreads();
  if (kc == 1){
#pragma unroll
    for (int m2 = 0; m2 < 2; m2++)
#pragma unroll
      for (int nt = 0; nt < 4; nt++)
        *(v4f*)(&s_acc[(nt * 16 + col) * 68 + mh * 32 + m2 * 16 + kg * 4]) = acc[m2][nt];
  }
  __syncthreads();
  if (kc == 0){
    float pav = pa[0];
#pragma unroll
    for (int m2 = 0; m2 < 2; m2++){
#pragma unroll
      for (int nt = 0; nt < 4; nt++){
        v4f other = *(const v4f*)(&s_acc[(nt * 16 + col) * 68 + mh * 32 + m2 * 16 + kg * 4]);
        v4f sum = acc[m2][nt] + other;
        int n = vb + nt * 16 + col;
#pragma unroll
        for (int r = 0; r < 4; r++){
          int o = mh * 32 + m2 * 16 + kg * 4 + r;
          float val = sum[r] + s_bias[ki4[nt] * 64 + o];
          val = (val >= 0.f) ? val : pav * val;
          size_t off = (size_t)o * NVOX + n;
          out[off] = val + x[off];
        }
      }
    }
  }
}

extern "C" void kernel_launch(void* const* d_in, const int* in_sizes, int n_in,
                              void* d_out, int out_size, void* d_ws, size_t ws_size,
                              hipStream_t stream){
  const float* x    = (const float*)d_in[0];
  const float* pw   = (const float*)d_in[1];
  const float* bw   = (const float*)d_in[2];
  const float* gkw1 = (const float*)d_in[3];
  const float* gkb1 = (const float*)d_in[4];
  const float* gkw2 = (const float*)d_in[5];
  const float* gkb2 = (const float*)d_in[6];
  const float* gkw3 = (const float*)d_in[7];
  const float* gkb3 = (const float*)d_in[8];
  const float* gbw1 = (const float*)d_in[9];
  const float* gbb1 = (const float*)d_in[10];
  const float* gbw2 = (const float*)d_in[11];
  const float* gbb2 = (const float*)d_in[12];
  const float* gbw3 = (const float*)d_in[13];
  const float* gbb3 = (const float*)d_in[14];
  const float* pa   = (const float*)d_in[15];
  float* outp = (float*)d_out;

  float* ws   = (float*)d_ws;
  float* XP   = ws;                                  // 4,096,000 f ; reused as XMT
  float* BU2  = ws + 4096000;                        // 4,096,000 f (wh-filtered)
  short* XPT  = (short*)(ws + 12288000);             // 4,741,632 s
  short* BWB  = XPT + (size_t)NPAD * 64;             // 110,592 s
  float* KM   = (float*)(BWB + 110592);              // 10*8320 f  (ACC[1..10])
  float* WI   = KM + 10 * ITST;                      // 108 f
  float* BIAS = WI + 108;                            // 256 f
  int*   IDX  = (int*)(BIAS + 256);                  // 64,000 i
  float* XMT  = XP;                                  // xm transposed [n][c]

  prep_k<<<1554, 256, 0, stream>>>(x, pw, XP, XPT, bw, BWB, KM);
  boxwh_k<<<2560, 256, 0, stream>>>(XP, BU2);
  boxdt_k<<<1000, 256, 0, stream>>>(BU2, XMT, KM);
  for (int it = 1; it <= 9; it++)
    assign_k<<<250, 256, 0, stream>>>(XMT, KM + (it - 1) * ITST, KM + it * ITST);
  fin_k<<<250, 256, 0, stream>>>(XMT, KM + 9 * ITST, IDX,
                                 gkw1, gkb1, gkw2, gkb2, gkw3, gkb3,
                                 gbw1, gbb1, gbw2, gbb2, gbw3, gbb3,
                                 WI, BIAS);
  conv_k<<<1000, 256, 0, stream>>>(XPT, BWB, WI, BIAS, IDX, x, pa, outp);
}

// Round 15
// 295.149 us; speedup vs baseline: 1.1801x; 1.0185x over previous
//
#include <hip/hip_runtime.h>
#include <math.h>

typedef short v8s __attribute__((ext_vector_type(8)));
typedef float v4f __attribute__((ext_vector_type(4)));

#define NVOX 64000      // 40^3
#define NPAD 74088      // 42^3
#define P2   1764       // 42^2
#define GSTR 592704     // NPAD*8
#define NCPY 32         // banked global-accumulator copies
#define ITST (NCPY*260) // stride per kmeans iteration (8320 floats)

__device__ __forceinline__ unsigned short bf16rne(float f){
  unsigned int u = __float_as_uint(f);
  u += 0x7FFFu + ((u >> 16) & 1u);
  return (unsigned short)(u >> 16);
}

// ---------------- merged prep: projection (blocks 0..999, 4-way channel split,
// XCD-swizzled so the 4 quarter-blocks of a voxel group share one XCD's L2)
// + base_w bf16 repack (1000..1431) + xpt halo zeroing (1432..1471)
// + KM accumulator zeroing (1472..1553).
__global__ __launch_bounds__(256) void prep_k(const float* __restrict__ x,
                                              const float* __restrict__ pw,
                                              float* __restrict__ xp,
                                              short* __restrict__ xpt,
                                              const float* __restrict__ bw,
                                              short* __restrict__ bwb,
                                              float* __restrict__ km){
  int tid = threadIdx.x;
  int bid = blockIdx.x;
  if (bid < 1000){
    // bijective XCD swizzle: 1000 = 8 XCDs x 125 consecutive jobs
    int j = (bid & 7) * 125 + (bid >> 3);
    int m = (j >> 2) * 256 + tid;
    int quarter = j & 3;
    float xv[64];
#pragma unroll
    for (int i = 0; i < 64; i++) xv[i] = x[(size_t)i * NVOX + m];
    int d = m / 1600; int r = m - d * 1600; int h = r / 40; int w = r - h * 40;
    int p = ((d + 1) * 42 + (h + 1)) * 42 + (w + 1);
    const float4* pw4 = (const float4*)pw;
    for (int g8 = quarter * 2; g8 < quarter * 2 + 2; g8++){
      v8s pk;
#pragma unroll
      for (int jj = 0; jj < 8; jj++){
        int co = g8 * 8 + jj;
        float acc = 0.f;
#pragma unroll
        for (int q = 0; q < 16; q++){
          float4 pv = pw4[co * 16 + q];   // wave-uniform -> scalar K$ loads
          acc = fmaf(pv.x, xv[4*q+0], acc);
          acc = fmaf(pv.y, xv[4*q+1], acc);
          acc = fmaf(pv.z, xv[4*q+2], acc);
          acc = fmaf(pv.w, xv[4*q+3], acc);
        }
        xp[(size_t)co * NVOX + m] = acc;
        pk[jj] = (short)bf16rne(acc);
      }
      *(v8s*)(xpt + (size_t)g8 * GSTR + (size_t)p * 8) = pk;
    }
  } else if (bid < 1432){
    int e = (bid - 1000) * 256 + tid;               // 0 .. 110591
    int t5 = e >> 12; int rem = e & 4095;
    int o = rem >> 6; int c = rem & 63;
    bwb[e] = (short)bf16rne(bw[(o * 64 + c) * 27 + t5]);
  } else if (bid < 1472){
    v8s z = (v8s){0,0,0,0,0,0,0,0};
    for (int p = (bid - 1432) * 256 + tid; p < NPAD; p += 40 * 256){
      int d = p / P2; int rem = p - d * P2; int h = rem / 42; int w = rem - h * 42;
      if (d == 0 || d == 41 || h == 0 || h == 41 || w == 0 || w == 41){
#pragma unroll
        for (int g = 0; g < 8; g++)
          *(v8s*)(xpt + (size_t)g * GSTR + (size_t)p * 8) = z;
      }
    }
  } else {
    for (int j = (bid - 1472) * 256 + tid; j < 10 * ITST; j += 82 * 256)
      km[j] = 0.f;
  }
}

// ---------------- fused w+h box passes per (c,d) slice (zero pad) — R6-proven
__global__ __launch_bounds__(256) void boxwh_k(const float* __restrict__ in,
                                               float* __restrict__ out){
  __shared__ float s0[1600], s1[1600];
  size_t base = (size_t)blockIdx.x * 1600;
  int t = threadIdx.x;
  for (int e = t; e < 1600; e += 256) s0[e] = in[base + e];
  __syncthreads();
  for (int e = t; e < 1600; e += 256){
    int w = e % 40;
    float s = s0[e];
    if (w > 0)  s += s0[e - 1];
    if (w < 39) s += s0[e + 1];
    s1[e] = s;
  }
  __syncthreads();
  for (int e = t; e < 1600; e += 256){
    int h = e / 40;
    float s = s1[e];
    if (h > 0)  s += s1[e - 40];
    if (h < 39) s += s1[e + 40];
    out[base + e] = s;
  }
}

// ---------------- fused boxd + transpose + kmeans-iter0 (R10-proven).
__global__ __launch_bounds__(256) void boxdt_k(const float* __restrict__ in,
                                               float* __restrict__ out,
                                               float* __restrict__ acc1){
  __shared__ float tile[64][65];
  __shared__ float s_cent[256];
  __shared__ float s_cc[4];
  __shared__ float s_red[260];
  __shared__ int   s_kb[64];
  int t = threadIdx.x;
  int nb = blockIdx.x * 64;
  int l = t & 63, g = t >> 6;
  {
    int k = t >> 6, c = t & 63;   // cent0[k][c] = (BU2[c][k] + BU2[c][k+1600])/27 (d=0)
    s_cent[t] = (in[(size_t)c * NVOX + k] + in[(size_t)c * NVOX + k + 1600]) * (1.f / 27.f);
  }
  for (int j = t; j < 260; j += 256) s_red[j] = 0.f;
  int n = nb + l;
  int d = n / 1600;
  for (int cc = g; cc < 64; cc += 4){
    const float* b = in + (size_t)cc * NVOX + n;
    float s = b[0];
    if (d > 0)  s += b[-1600];
    if (d < 39) s += b[1600];
    tile[cc][l] = s * (1.f / 27.f);
  }
  __syncthreads();
  if (t < 4){
    float s = 0.f;
    for (int c = 0; c < 64; c++){ float v = s_cent[t * 64 + c]; s = fmaf(v, v, s); }
    s_cc[t] = s;
  }
  __syncthreads();
  if (t < 64){
    float d0 = 0.f, d1 = 0.f, d2 = 0.f, d3 = 0.f;
    for (int c = 0; c < 64; c++){
      float v = tile[c][t];
      d0 = fmaf(s_cent[c], v, d0);
      d1 = fmaf(s_cent[64 + c], v, d1);
      d2 = fmaf(s_cent[128 + c], v, d2);
      d3 = fmaf(s_cent[192 + c], v, d3);
    }
    float sc0 = s_cc[0] - 2.f * d0;
    float sc1 = s_cc[1] - 2.f * d1;
    float sc2 = s_cc[2] - 2.f * d2;
    float sc3 = s_cc[3] - 2.f * d3;
    int kb = 0; float bs = sc0;
    if (sc1 < bs){ bs = sc1; kb = 1; }
    if (sc2 < bs){ bs = sc2; kb = 2; }
    if (sc3 < bs){ bs = sc3; kb = 3; }
    s_kb[t] = kb;
  }
  __syncthreads();
  {
    int lane = t & 63, wv = t >> 6;
    float a0 = 0.f, a1 = 0.f, a2 = 0.f, a3 = 0.f;
#pragma unroll
    for (int j = 0; j < 16; j++){
      int p = wv * 16 + j;
      float v = tile[lane][p];
      int kj = s_kb[p];
      a0 += (kj == 0) ? v : 0.f;
      a1 += (kj == 1) ? v : 0.f;
      a2 += (kj == 2) ? v : 0.f;
      a3 += (kj == 3) ? v : 0.f;
    }
    atomicAdd(&s_red[lane], a0);
    atomicAdd(&s_red[64 + lane], a1);
    atomicAdd(&s_red[128 + lane], a2);
    atomicAdd(&s_red[192 + lane], a3);
  }
  if (t < 4){
    float c = 0.f;
    for (int p = 0; p < 64; p++) c += (s_kb[p] == t) ? 1.f : 0.f;
    s_red[256 + t] = c;     // single writer per slot
  }
  __syncthreads();
  float* kslot = acc1 + (blockIdx.x & (NCPY - 1)) * 260;
  for (int j = t; j < 260; j += 256) atomicAdd(&kslot[j], s_red[j]);
  for (int nn = g; nn < 64; nn += 4)
    out[(size_t)(nb + nn) * 64 + l] = tile[l][nn];
}

// ---------------- kmeans assign + reduce (iters 1..9)
__global__ __launch_bounds__(256) void assign_k(const float* __restrict__ xmt,
                                                const float* __restrict__ kin,
                                                float* __restrict__ kout){
  __shared__ float s_cent[256];
  __shared__ float s_cc[4];
  __shared__ float s_red[260];
  __shared__ float s_x[256 * 65];
  __shared__ int   s_kb[256];
  int t = threadIdx.x, lane = t & 63, wv = t >> 6;
  int n = blockIdx.x * 256 + t;
  {
    float sum = 0.f, cnt = 0.f;
#pragma unroll
    for (int s = 0; s < NCPY; s++){
      sum += kin[s * 260 + t];
      cnt += kin[s * 260 + 256 + (t >> 6)];
    }
    s_cent[t] = sum / fmaxf(cnt, 1.f);
  }
  for (int j = t; j < 260; j += 256) s_red[j] = 0.f;
  __syncthreads();
  if (t < 4){
    const float4* cc4 = (const float4*)(s_cent + t * 64);
    float s = 0.f;
#pragma unroll
    for (int q = 0; q < 16; q++){
      float4 v = cc4[q];
      s = fmaf(v.x, v.x, s); s = fmaf(v.y, v.y, s);
      s = fmaf(v.z, v.z, s); s = fmaf(v.w, v.w, s);
    }
    s_cc[t] = s;
  }
  __syncthreads();
  const float4* xt = (const float4*)(xmt + (size_t)n * 64);
  float4 xq[16];
#pragma unroll
  for (int q = 0; q < 16; q++) xq[q] = xt[q];
  float d0 = 0.f, d1 = 0.f, d2 = 0.f, d3 = 0.f;
  const float4* c4 = (const float4*)s_cent;
#pragma unroll
  for (int q = 0; q < 16; q++){
    float4 p0 = c4[q], p1 = c4[16 + q], p2 = c4[32 + q], p3 = c4[48 + q];
    d0 = fmaf(p0.x, xq[q].x, d0); d0 = fmaf(p0.y, xq[q].y, d0);
    d0 = fmaf(p0.z, xq[q].z, d0); d0 = fmaf(p0.w, xq[q].w, d0);
    d1 = fmaf(p1.x, xq[q].x, d1); d1 = fmaf(p1.y, xq[q].y, d1);
    d1 = fmaf(p1.z, xq[q].z, d1); d1 = fmaf(p1.w, xq[q].w, d1);
    d2 = fmaf(p2.x, xq[q].x, d2); d2 = fmaf(p2.y, xq[q].y, d2);
    d2 = fmaf(p2.z, xq[q].z, d2); d2 = fmaf(p2.w, xq[q].w, d2);
    d3 = fmaf(p3.x, xq[q].x, d3); d3 = fmaf(p3.y, xq[q].y, d3);
    d3 = fmaf(p3.z, xq[q].z, d3); d3 = fmaf(p3.w, xq[q].w, d3);
  }
  float sc0 = s_cc[0] - 2.f * d0;
  float sc1 = s_cc[1] - 2.f * d1;
  float sc2 = s_cc[2] - 2.f * d2;
  float sc3 = s_cc[3] - 2.f * d3;
  int kb = 0; float bs = sc0;
  if (sc1 < bs){ bs = sc1; kb = 1; }
  if (sc2 < bs){ bs = sc2; kb = 2; }
  if (sc3 < bs){ bs = sc3; kb = 3; }
  s_kb[t] = kb;
#pragma unroll
  for (int q = 0; q < 16; q++){
    s_x[t * 65 + 4*q + 0] = xq[q].x;
    s_x[t * 65 + 4*q + 1] = xq[q].y;
    s_x[t * 65 + 4*q + 2] = xq[q].z;
    s_x[t * 65 + 4*q + 3] = xq[q].w;
  }
  __syncthreads();
  float a0 = 0.f, a1 = 0.f, a2 = 0.f, a3 = 0.f;
  int rowbase = wv * 64;
#pragma unroll 16
  for (int j = 0; j < 64; j++){
    float v = s_x[(rowbase + j) * 65 + lane];
    int kj = s_kb[rowbase + j];
    a0 += (kj == 0) ? v : 0.f;
    a1 += (kj == 1) ? v : 0.f;
    a2 += (kj == 2) ? v : 0.f;
    a3 += (kj == 3) ? v : 0.f;
  }
  atomicAdd(&s_red[lane], a0);
  atomicAdd(&s_red[64 + lane], a1);
  atomicAdd(&s_red[128 + lane], a2);
  atomicAdd(&s_red[192 + lane], a3);
#pragma unroll
  for (int kk = 0; kk < 4; kk++){
    unsigned long long m = __ballot(kb == kk);
    if (lane == 0) atomicAdd(&s_red[256 + kk], (float)__popcll(m));
  }
  __syncthreads();
  float* kslot = kout + (blockIdx.x & (NCPY - 1)) * 260;
  for (int j = t; j < 260; j += 256) atomicAdd(&kslot[j], s_red[j]);
}

// ---------------- finalize: cent10 -> idx (all blocks) + gating MLPs (block 0,
// parallel form: 4-acc ILP, h-path/g-path on disjoint warps). R14-proven.
__global__ __launch_bounds__(256) void fin_k(const float* __restrict__ xmt,
                                             const float* __restrict__ kin,
                                             int* __restrict__ idx,
                      const float* __restrict__ w1, const float* __restrict__ b1,
                      const float* __restrict__ w2, const float* __restrict__ b2,
                      const float* __restrict__ w3, const float* __restrict__ b3,
                      const float* __restrict__ u1, const float* __restrict__ c1,
                      const float* __restrict__ u2, const float* __restrict__ c2,
                      const float* __restrict__ u3, const float* __restrict__ c3,
                      float* __restrict__ wi, float* __restrict__ bias){
  __shared__ float s_cent[256];
  __shared__ float s_cc[4];
  __shared__ float s_h1[128], s_h2[128], s_g1[64], s_g2[64];
  int t = threadIdx.x;
  int n = blockIdx.x * 256 + t;
  {
    float sum = 0.f, cnt = 0.f;
#pragma unroll
    for (int s = 0; s < NCPY; s++){
      sum += kin[s * 260 + t];
      cnt += kin[s * 260 + 256 + (t >> 6)];
    }
    s_cent[t] = sum / fmaxf(cnt, 1.f);
  }
  __syncthreads();
  if (t < 4){
    const float4* cc4 = (const float4*)(s_cent + t * 64);
    float s = 0.f;
#pragma unroll
    for (int q = 0; q < 16; q++){
      float4 v = cc4[q];
      s = fmaf(v.x, v.x, s); s = fmaf(v.y, v.y, s);
      s = fmaf(v.z, v.z, s); s = fmaf(v.w, v.w, s);
    }
    s_cc[t] = s;
  }
  __syncthreads();
  {
    const float4* xt = (const float4*)(xmt + (size_t)n * 64);
    float4 xq[16];
#pragma unroll
    for (int q = 0; q < 16; q++) xq[q] = xt[q];
    float d0 = 0.f, d1 = 0.f, d2 = 0.f, d3 = 0.f;
    const float4* c4 = (const float4*)s_cent;
#pragma unroll
    for (int q = 0; q < 16; q++){
      float4 p0 = c4[q], p1 = c4[16 + q], p2 = c4[32 + q], p3 = c4[48 + q];
      d0 = fmaf(p0.x, xq[q].x, d0); d0 = fmaf(p0.y, xq[q].y, d0);
      d0 = fmaf(p0.z, xq[q].z, d0); d0 = fmaf(p0.w, xq[q].w, d0);
      d1 = fmaf(p1.x, xq[q].x, d1); d1 = fmaf(p1.y, xq[q].y, d1);
      d1 = fmaf(p1.z, xq[q].z, d1); d1 = fmaf(p1.w, xq[q].w, d1);
      d2 = fmaf(p2.x, xq[q].x, d2); d2 = fmaf(p2.y, xq[q].y, d2);
      d2 = fmaf(p2.z, xq[q].z, d2); d2 = fmaf(p2.w, xq[q].w, d2);
      d3 = fmaf(p3.x, xq[q].x, d3); d3 = fmaf(p3.y, xq[q].y, d3);
      d3 = fmaf(p3.z, xq[q].z, d3); d3 = fmaf(p3.w, xq[q].w, d3);
    }
    float sc0 = s_cc[0] - 2.f * d0;
    float sc1 = s_cc[1] - 2.f * d1;
    float sc2 = s_cc[2] - 2.f * d2;
    float sc3 = s_cc[3] - 2.f * d3;
    int kb = 0; float bs = sc0;
    if (sc1 < bs){ bs = sc1; kb = 1; }
    if (sc2 < bs){ bs = sc2; kb = 2; }
    if (sc3 < bs){ bs = sc3; kb = 3; }
    idx[n] = kb;
  }
  if (blockIdx.x != 0) return;
  // ---- gating MLPs (parallel form)
  if (t < 128){
    float z0 = 0.f, z1 = 0.f, z2 = 0.f, z3 = 0.f;
#pragma unroll 4
    for (int i = 0; i < 256; i += 4){
      z0 = fmaf(s_cent[i + 0], w1[(i + 0) * 128 + t], z0);
      z1 = fmaf(s_cent[i + 1], w1[(i + 1) * 128 + t], z1);
      z2 = fmaf(s_cent[i + 2], w1[(i + 2) * 128 + t], z2);
      z3 = fmaf(s_cent[i + 3], w1[(i + 3) * 128 + t], z3);
    }
    s_h1[t] = fmaxf(b1[t] + ((z0 + z1) + (z2 + z3)), 0.f);
  } else if (t < 192){
    int t6 = t - 128;
    float z0 = 0.f, z1 = 0.f, z2 = 0.f, z3 = 0.f;
#pragma unroll 4
    for (int i = 0; i < 256; i += 4){
      z0 = fmaf(s_cent[i + 0], u1[(i + 0) * 64 + t6], z0);
      z1 = fmaf(s_cent[i + 1], u1[(i + 1) * 64 + t6], z1);
      z2 = fmaf(s_cent[i + 2], u1[(i + 2) * 64 + t6], z2);
      z3 = fmaf(s_cent[i + 3], u1[(i + 3) * 64 + t6], z3);
    }
    s_g1[t6] = fmaxf(c1[t6] + ((z0 + z1) + (z2 + z3)), 0.f);
  }
  __syncthreads();
  if (t < 128){
    float z0 = 0.f, z1 = 0.f, z2 = 0.f, z3 = 0.f;
#pragma unroll 4
    for (int i = 0; i < 128; i += 4){
      z0 = fmaf(s_h1[i + 0], w2[(i + 0) * 128 + t], z0);
      z1 = fmaf(s_h1[i + 1], w2[(i + 1) * 128 + t], z1);
      z2 = fmaf(s_h1[i + 2], w2[(i + 2) * 128 + t], z2);
      z3 = fmaf(s_h1[i + 3], w2[(i + 3) * 128 + t], z3);
    }
    s_h2[t] = fmaxf(b2[t] + ((z0 + z1) + (z2 + z3)), 0.f);
  } else if (t < 192){
    int t6 = t - 128;
    float z0 = 0.f, z1 = 0.f, z2 = 0.f, z3 = 0.f;
#pragma unroll 4
    for (int i = 0; i < 64; i += 4){
      z0 = fmaf(s_g1[i + 0], u2[(i + 0) * 64 + t6], z0);
      z1 = fmaf(s_g1[i + 1], u2[(i + 1) * 64 + t6], z1);
      z2 = fmaf(s_g1[i + 2], u2[(i + 2) * 64 + t6], z2);
      z3 = fmaf(s_g1[i + 3], u2[(i + 3) * 64 + t6], z3);
    }
    s_g2[t6] = fmaxf(c2[t6] + ((z0 + z1) + (z2 + z3)), 0.f);
  }
  __syncthreads();
  if (t < 108){
    float z0 = 0.f, z1 = 0.f, z2 = 0.f, z3 = 0.f;
#pragma unroll 4
    for (int i = 0; i < 128; i += 4){
      z0 = fmaf(s_h2[i + 0], w3[(i + 0) * 108 + t], z0);
      z1 = fmaf(s_h2[i + 1], w3[(i + 1) * 108 + t], z1);
      z2 = fmaf(s_h2[i + 2], w3[(i + 2) * 108 + t], z2);
      z3 = fmaf(s_h2[i + 3], w3[(i + 3) * 108 + t], z3);
    }
    float z = b3[t] + ((z0 + z1) + (z2 + z3));
    wi[t] = 1.f / (1.f + expf(-z));
  }
  {
    float z0 = 0.f, z1 = 0.f, z2 = 0.f, z3 = 0.f;
#pragma unroll 4
    for (int i = 0; i < 64; i += 4){
      z0 = fmaf(s_g2[i + 0], u3[(i + 0) * 256 + t], z0);
      z1 = fmaf(s_g2[i + 1], u3[(i + 1) * 256 + t], z1);
      z2 = fmaf(s_g2[i + 2], u3[(i + 2) * 256 + t], z2);
      z3 = fmaf(s_g2[i + 3], u3[(i + 3) * 256 + t], z3);
    }
    bias[t] = c3[t] + ((z0 + z1) + (z2 + z3));
  }
}

// ---------------- main dynamic conv (R6-proven body; XCD-swizzled tile order:
// each XCD gets 125 consecutive 64-voxel tiles so overlapping xpt halos stay
// in the same per-XCD L2 instead of bouncing to L3/HBM).
__global__ __launch_bounds__(256) void conv_k(const short* __restrict__ xpt,
                                              const short* __restrict__ bwb,
                                              const float* __restrict__ wi,
                                              const float* __restrict__ bias,
                                              const int* __restrict__ idx,
                                              const float* __restrict__ x,
                                              const float* __restrict__ pa,
                                              float* __restrict__ out){
  static const int POFF[27] = {
    -P2-42-1, -P2-42, -P2-42+1, -P2-1, -P2, -P2+1, -P2+42-1, -P2+42, -P2+42+1,
    -42-1, -42, -42+1, -1, 0, 1, 42-1, 42, 42+1,
    P2-42-1, P2-42, P2-42+1, P2-1, P2, P2+1, P2+42-1, P2+42, P2+42+1 };
  __shared__ float s_wi[108];
  __shared__ float s_bias[256];
  __shared__ float s_acc[64 * 68];
  int tid = threadIdx.x;
  for (int j = tid; j < 108; j += 256) s_wi[j] = wi[j];
  s_bias[tid] = bias[tid];
  __syncthreads();
  int wv = tid >> 6, lane = tid & 63;
  int kc = wv & 1, mh = wv >> 1;
  int col = lane & 15, kg = lane >> 4;
  int bidx = (int)blockIdx.x;
  int vb = ((bidx & 7) * 125 + (bidx >> 3)) * 64;   // bijective XCD swizzle
  int p4[4], ki4[4];
#pragma unroll
  for (int nt = 0; nt < 4; nt++){
    int v = vb + nt * 16 + col;
    ki4[nt] = idx[v];
    int d = v / 1600; int r = v - d * 1600; int h = r / 40; int w = r - h * 40;
    p4[nt] = ((d + 1) * 42 + (h + 1)) * 42 + (w + 1);
  }
  const short* bg = xpt + (size_t)(kc * 4 + kg) * GSTR;
  const short* bp0 = bg + (size_t)p4[0] * 8;
  const short* bp1 = bg + (size_t)p4[1] * 8;
  const short* bp2 = bg + (size_t)p4[2] * 8;
  const short* bp3 = bg + (size_t)p4[3] * 8;
  int ao0 = (mh * 32 + col) * 64 + kc * 32 + kg * 8;
  int ao1 = ao0 + 16 * 64;
  v4f acc[2][4];
#pragma unroll
  for (int m2 = 0; m2 < 2; m2++)
#pragma unroll
    for (int nt = 0; nt < 4; nt++) acc[m2][nt] = (v4f){0.f, 0.f, 0.f, 0.f};
  v4f zero = {0.f, 0.f, 0.f, 0.f};
#pragma unroll 9
  for (int t = 0; t < 27; t++){
    int po8 = POFF[t] * 8;
    v8s a0 = *(const v8s*)(bwb + t * 4096 + ao0);
    v8s a1 = *(const v8s*)(bwb + t * 4096 + ao1);
    v8s b0 = *(const v8s*)(bp0 + po8);
    v8s b1 = *(const v8s*)(bp1 + po8);
    v8s b2 = *(const v8s*)(bp2 + po8);
    v8s b3 = *(const v8s*)(bp3 + po8);
    float wk0 = s_wi[ki4[0] * 27 + t];
    float wk1 = s_wi[ki4[1] * 27 + t];
    float wk2 = s_wi[ki4[2] * 27 + t];
    float wk3 = s_wi[ki4[3] * 27 + t];
    v4f tp;
    tp = __builtin_amdgcn_mfma_f32_16x16x32_bf16(a0, b0, zero, 0, 0, 0); acc[0][0] += tp * wk0;
    tp = __builtin_amdgcn_mfma_f32_16x16x32_bf16(a1, b0, zero, 0, 0, 0); acc[1][0] += tp * wk0;
    tp = __builtin_amdgcn_mfma_f32_16x16x32_bf16(a0, b1, zero, 0, 0, 0); acc[0][1] += tp * wk1;
    tp = __builtin_amdgcn_mfma_f32_16x16x32_bf16(a1, b1, zero, 0, 0, 0); acc[1][1] += tp * wk1;
    tp = __builtin_amdgcn_mfma_f32_16x16x32_bf16(a0, b2, zero, 0, 0, 0); acc[0][2] += tp * wk2;
    tp = __builtin_amdgcn_mfma_f32_16x16x32_bf16(a1, b2, zero, 0, 0, 0); acc[1][2] += tp * wk2;
    tp = __builtin_amdgcn_mfma_f32_16x16x32_bf16(a0, b3, zero, 0, 0, 0); acc[0][3] += tp * wk3;
    tp = __builtin_amdgcn_mfma_f32_16x16x32_bf16(a1, b3, zero, 0, 0, 0); acc[1][3] += tp * wk3;
  }
  __syncthreads();
  if (kc == 1){
#pragma unroll
    for (int m2 = 0; m2 < 2; m2++)
#pragma unroll
      for (int nt = 0; nt < 4; nt++)
        *(v4f*)(&s_acc[(nt * 16 + col) * 68 + mh * 32 + m2 * 16 + kg * 4]) = acc[m2][nt];
  }
  __syncthreads();
  if (kc == 0){
    float pav = pa[0];
#pragma unroll
    for (int m2 = 0; m2 < 2; m2++){
#pragma unroll
      for (int nt = 0; nt < 4; nt++){
        v4f other = *(const v4f*)(&s_acc[(nt * 16 + col) * 68 + mh * 32 + m2 * 16 + kg * 4]);
        v4f sum = acc[m2][nt] + other;
        int n = vb + nt * 16 + col;
#pragma unroll
        for (int r = 0; r < 4; r++){
          int o = mh * 32 + m2 * 16 + kg * 4 + r;
          float val = sum[r] + s_bias[ki4[nt] * 64 + o];
          val = (val >= 0.f) ? val : pav * val;
          size_t off = (size_t)o * NVOX + n;
          out[off] = val + x[off];
        }
      }
    }
  }
}

extern "C" void kernel_launch(void* const* d_in, const int* in_sizes, int n_in,
                              void* d_out, int out_size, void* d_ws, size_t ws_size,
                              hipStream_t stream){
  const float* x    = (const float*)d_in[0];
  const float* pw   = (const float*)d_in[1];
  const float* bw   = (const float*)d_in[2];
  const float* gkw1 = (const float*)d_in[3];
  const float* gkb1 = (const float*)d_in[4];
  const float* gkw2 = (const float*)d_in[5];
  const float* gkb2 = (const float*)d_in[6];
  const float* gkw3 = (const float*)d_in[7];
  const float* gkb3 = (const float*)d_in[8];
  const float* gbw1 = (const float*)d_in[9];
  const float* gbb1 = (const float*)d_in[10];
  const float* gbw2 = (const float*)d_in[11];
  const float* gbb2 = (const float*)d_in[12];
  const float* gbw3 = (const float*)d_in[13];
  const float* gbb3 = (const float*)d_in[14];
  const float* pa   = (const float*)d_in[15];
  float* outp = (float*)d_out;

  float* ws   = (float*)d_ws;
  float* XP   = ws;                                  // 4,096,000 f ; reused as XMT
  float* BU2  = ws + 4096000;                        // 4,096,000 f (wh-filtered)
  short* XPT  = (short*)(ws + 12288000);             // 4,741,632 s
  short* BWB  = XPT + (size_t)NPAD * 64;             // 110,592 s
  float* KM   = (float*)(BWB + 110592);              // 10*8320 f  (ACC[1..10])
  float* WI   = KM + 10 * ITST;                      // 108 f
  float* BIAS = WI + 108;                            // 256 f
  int*   IDX  = (int*)(BIAS + 256);                  // 64,000 i
  float* XMT  = XP;                                  // xm transposed [n][c]

  prep_k<<<1554, 256, 0, stream>>>(x, pw, XP, XPT, bw, BWB, KM);
  boxwh_k<<<2560, 256, 0, stream>>>(XP, BU2);
  boxdt_k<<<1000, 256, 0, stream>>>(BU2, XMT, KM);
  for (int it = 1; it <= 9; it++)
    assign_k<<<250, 256, 0, stream>>>(XMT, KM + (it - 1) * ITST, KM + it * ITST);
  fin_k<<<250, 256, 0, stream>>>(XMT, KM + 9 * ITST, IDX,
                                 gkw1, gkb1, gkw2, gkb2, gkw3, gkb3,
                                 gbw1, gbb1, gbw2, gbb2, gbw3, gbb3,
                                 WI, BIAS);
  conv_k<<<1000, 256, 0, stream>>>(XPT, BWB, WI, BIAS, IDX, x, pa, outp);
}